// Round 5
// baseline (233.865 us; speedup 1.0000x reference)
//
#include <hip/hip_runtime.h>
#include <hip/hip_bf16.h>

// BertSelfAttention B=4,S=1024,HID=1024,H=16,D=64,MAXP=1024 — Round 12.
// R11 post-mortem: occupancy pinned at ~18% by grid (8 waves/CU) in EVERY
// config tried -> only lever is per-wave critical path. R11 still stalls:
// K loaded at iter top, consumed by first MFMA (L2 latency naked on the
// critical path x16 iters); ring reads issued mid-softmax.
// R12: explicit cross-iteration software pipeline:
//  - kb double-buffered in regs (issued one full iteration ahead)
//  - tr ring-reads prefetched at end of prev iter (after production; same-
//    wave in-order LDS)
//  - V/pb issued several hundred cycles before use
//  - s_setprio(1) around MFMA clusters (T5; barrier-free kernel = the regime
//    where it pays)
//  - qkv K-loop: explicit 2-deep register double-buffer (same disease).
// Reg budget ~230 peak, cap 256 via (256,2). Spill alarm: WRITE_SIZE >17MB.
// ws: Xs[0,8M) Wt[8M,14M) Db[14M,14.25M) Qf[15M) Kf[23M) Vt[31M)

#define EPSV 1e-8f

typedef short bfrag __attribute__((ext_vector_type(8)));   // 8 bf16
typedef float cfrag __attribute__((ext_vector_type(16)));  // C/D 32x32
typedef int v2i __attribute__((ext_vector_type(2)));

__device__ __forceinline__ short f2bf(float f) {
    __hip_bfloat16 h = __float2bfloat16(f);
    return *reinterpret_cast<short*>(&h);
}
__device__ __forceinline__ unsigned int pk2(short a, short b) {
    return (unsigned int)(unsigned short)a | ((unsigned int)(unsigned short)b << 16);
}

// ---------------------------------------------------------------------------
// prep: fused cvt/swizzle. grid.x = 3648, 256 thr.
__global__ __launch_bounds__(256) void prep(
    const float* __restrict__ hidden, const float* __restrict__ Wq,
    const float* __restrict__ Wk, const float* __restrict__ Wv,
    const float* __restrict__ dist,
    short* __restrict__ Xs, short* __restrict__ Wt, short* __restrict__ Db)
{
    __shared__ short Tl[32 * 72];
    const int bid = blockIdx.x, tid = threadIdx.x;

    if (bid < 2048) {                      // X: 128 m-tiles x 16 k-groups
        const int mt = bid >> 4, kg = bid & 15;
        const int m_l = tid >> 3, k8 = (tid & 7) * 8;
        const float* src = hidden + (size_t)(mt * 32 + m_l) * 1024 + kg * 64 + k8;
        float4 v0 = *(const float4*)src, v1 = *(const float4*)(src + 4);
        short o[8];
        o[0] = f2bf(v0.x); o[1] = f2bf(v0.y); o[2] = f2bf(v0.z); o[3] = f2bf(v0.w);
        o[4] = f2bf(v1.x); o[5] = f2bf(v1.y); o[6] = f2bf(v1.z); o[7] = f2bf(v1.w);
        *(bfrag*)&Tl[m_l * 72 + k8] = *(bfrag*)o;
        __syncthreads();
        const int l31 = tid & 31, q2 = (tid >> 5) & 1, kc = tid >> 6;
        bfrag r = *(const bfrag*)&Tl[l31 * 72 + kc * 16 + q2 * 8];
        *(bfrag*)(Xs + ((size_t)(mt * 64 + kg * 4 + kc) * 64 + q2 * 32 + l31) * 8) = r;
    } else if (bid < 3584) {               // W: 3 z x 32 n-tiles x 16 k-groups
        const int t = bid - 2048, z = t >> 9, nt = (t >> 4) & 31, kg = t & 15;
        const float* W = (z == 0) ? Wq : ((z == 1) ? Wk : Wv);
        const int k_l = tid >> 2, n8 = (tid & 3) * 8;
        const float* src = W + (size_t)(kg * 64 + k_l) * 1024 + nt * 32 + n8;
        float4 v0 = *(const float4*)src, v1 = *(const float4*)(src + 4);
        float vv[8] = {v0.x, v0.y, v0.z, v0.w, v1.x, v1.y, v1.z, v1.w};
#pragma unroll
        for (int i = 0; i < 8; i++)
            Tl[(n8 + i) * 72 + k_l] = f2bf(vv[i]);   // transpose into LDS
        __syncthreads();
        const int l31 = tid & 31, q2 = (tid >> 5) & 1, kc = tid >> 6;
        bfrag r = *(const bfrag*)&Tl[l31 * 72 + kc * 16 + q2 * 8];
        *(bfrag*)(Wt + (size_t)z * 1048576
                  + ((size_t)(nt * 64 + kg * 4 + kc) * 64 + q2 * 32 + l31) * 8) = r;
    } else {                               // dist: 2047*64 = 131008 elems
        const int idx = (bid - 3584) * 256 + tid;
        if (idx < 16376) {
            const float* src = dist + (size_t)idx * 8;
            float4 v0 = *(const float4*)src, v1 = *(const float4*)(src + 4);
            short o[8];
            o[0] = f2bf(v0.x); o[1] = f2bf(v0.y); o[2] = f2bf(v0.z); o[3] = f2bf(v0.w);
            o[4] = f2bf(v1.x); o[5] = f2bf(v1.y); o[6] = f2bf(v1.z); o[7] = f2bf(v1.w);
            *(bfrag*)(Db + (size_t)idx * 8) = *(bfrag*)o;
        }
    }
}

// ---------------------------------------------------------------------------
// QKV GEMM, LDS-free. 128x128 block, 4 waves 2x2 of 64x64.
// K-loop explicitly double-buffered (load group k+1 while MFMA group k).
__global__ __launch_bounds__(256) void qkv_mfma(
    const short* __restrict__ Xs, const short* __restrict__ Wt,
    const float* __restrict__ bq, const float* __restrict__ bk,
    const float* __restrict__ bv,
    short* __restrict__ Qf, short* __restrict__ Kf, short* __restrict__ Vt)
{
    const int z = blockIdx.z;
    const short* W = Wt + (size_t)z * 1048576;
    const float* bias = (z == 0) ? bq : ((z == 1) ? bk : bv);
    // fold 1/sqrt(D) AND log2(e) into Q: 0.125 * 1.4426950408889634
    const float scale = (z == 0) ? 0.18033688011112042f : 1.0f;

    const int tid = threadIdx.x, lane = tid & 63, wid = tid >> 6;
    const int q2 = lane >> 5, l31 = lane & 31;
    const int wr = wid >> 1, wc = wid & 1;
    const int m0 = blockIdx.x * 128, n0 = blockIdx.y * 128;

    cfrag acc[2][2];
#pragma unroll
    for (int i = 0; i < 2; i++)
#pragma unroll
        for (int j = 0; j < 2; j++)
#pragma unroll
            for (int e = 0; e < 16; e++) acc[i][j][e] = 0.f;

    const short* ap0 = Xs + ((size_t)((m0 >> 5) + wr * 2 + 0) * 64 * 64 + lane) * 8;
    const short* ap1 = Xs + ((size_t)((m0 >> 5) + wr * 2 + 1) * 64 * 64 + lane) * 8;
    const short* bp0 = W  + ((size_t)((n0 >> 5) + wc * 2 + 0) * 64 * 64 + lane) * 8;
    const short* bp1 = W  + ((size_t)((n0 >> 5) + wc * 2 + 1) * 64 * 64 + lane) * 8;

    bfrag a0c, a1c, b0c, b1c, a0n, a1n, b0n, b1n;
    a0c = *(const bfrag*)(ap0); a1c = *(const bfrag*)(ap1);
    b0c = *(const bfrag*)(bp0); b1c = *(const bfrag*)(bp1);

#pragma unroll 2
    for (int kc = 0; kc < 64; kc += 2) {
        {   // prefetch group kc+1
            const int off = (kc + 1) * 512;
            a0n = *(const bfrag*)(ap0 + off); a1n = *(const bfrag*)(ap1 + off);
            b0n = *(const bfrag*)(bp0 + off); b1n = *(const bfrag*)(bp1 + off);
        }
        acc[0][0] = __builtin_amdgcn_mfma_f32_32x32x16_bf16(a0c, b0c, acc[0][0], 0, 0, 0);
        acc[0][1] = __builtin_amdgcn_mfma_f32_32x32x16_bf16(a0c, b1c, acc[0][1], 0, 0, 0);
        acc[1][0] = __builtin_amdgcn_mfma_f32_32x32x16_bf16(a1c, b0c, acc[1][0], 0, 0, 0);
        acc[1][1] = __builtin_amdgcn_mfma_f32_32x32x16_bf16(a1c, b1c, acc[1][1], 0, 0, 0);
        if (kc + 2 < 64) {   // prefetch group kc+2
            const int off = (kc + 2) * 512;
            a0c = *(const bfrag*)(ap0 + off); a1c = *(const bfrag*)(ap1 + off);
            b0c = *(const bfrag*)(bp0 + off); b1c = *(const bfrag*)(bp1 + off);
        }
        acc[0][0] = __builtin_amdgcn_mfma_f32_32x32x16_bf16(a0n, b0n, acc[0][0], 0, 0, 0);
        acc[0][1] = __builtin_amdgcn_mfma_f32_32x32x16_bf16(a0n, b1n, acc[0][1], 0, 0, 0);
        acc[1][0] = __builtin_amdgcn_mfma_f32_32x32x16_bf16(a1n, b0n, acc[1][0], 0, 0, 0);
        acc[1][1] = __builtin_amdgcn_mfma_f32_32x32x16_bf16(a1n, b1n, acc[1][1], 0, 0, 0);
    }

    // epilogue: +bias, (Q: x scale), cvt bf16, scatter frag-major per bh
#pragma unroll
    for (int nt = 0; nt < 2; nt++) {
        const int c = n0 + wc * 64 + nt * 32 + l31;    // channel
        const float bval = bias[c];
        const int h = c >> 6;
        const int d = nt * 32 + l31;                   // c & 63
#pragma unroll
        for (int mt = 0; mt < 2; mt++) {
            const int tok0 = m0 + wr * 64 + mt * 32;
            const int bb = tok0 >> 10, s_base = tok0 & 1023;
            const size_t bhbase = (size_t)(bb * 16 + h) * 65536;
            if (z < 2) {
                short* outp = (z == 0) ? Qf : Kf;
                const size_t fbase = bhbase
                    + ((size_t)((s_base >> 5) * 4 + (d >> 4)) * 64
                       + ((d >> 3) & 1) * 32) * 8 + (d & 7);
#pragma unroll
                for (int reg = 0; reg < 16; reg++) {
                    const int row = (reg & 3) + 8 * (reg >> 2) + 4 * q2;
                    outp[fbase + (size_t)row * 8] = f2bf((acc[mt][nt][reg] + bval) * scale);
                }
            } else {
                // V^T frag-major: elem (d, s): ((d>>5)*64 + (s>>4))*64*8 ...
#pragma unroll
                for (int g = 0; g < 4; g++) {
                    const float e0 = acc[mt][nt][4 * g + 0] + bval;
                    const float e1 = acc[mt][nt][4 * g + 1] + bval;
                    const float e2 = acc[mt][nt][4 * g + 2] + bval;
                    const float e3 = acc[mt][nt][4 * g + 3] + bval;
                    uint2 w2;
                    w2.x = pk2(f2bf(e0), f2bf(e1));
                    w2.y = pk2(f2bf(e2), f2bf(e3));
                    const size_t flat = bhbase
                        + ((size_t)(nt * 64 + (s_base >> 4) + (g >> 1)) * 64
                           + (g & 1) * 32 + l31) * 8 + 4 * q2;
                    *(uint2*)(Vt + flat) = w2;
                }
            }
        }
    }
}

// ---------------------------------------------------------------------------
// Fused attention. grid (64 bh, 8 l-tiles), 256 thr (4 waves).
// Wave w owns l-cols [l0+32w,+32) for all r. Barrier-free main loop.
// Ring indexed by r (row l31, slot r&127). Cross-iteration pipeline:
// kb double-buffered, tr prefetched at end of prev iter, production one
// window ahead (classic double-buffered half-ring).
__global__ __launch_bounds__(256, 2) void attn_mfma(
    const short* __restrict__ Qf, const short* __restrict__ Kf,
    const short* __restrict__ Vt, const short* __restrict__ Db,
    const float* __restrict__ amask, const int* __restrict__ skim,
    float* __restrict__ out)
{
    __shared__ short Tb[128 * 132];   // per-(wave,lane) r-ring, stride 132
    __shared__ float Lg[1024];        // g[r] = exp(amask)*skim

    const int tid = threadIdx.x, lane = tid & 63, w = tid >> 6;
    const int q2 = lane >> 5, l31 = lane & 31;
    const int bh = blockIdx.x, b = bh >> 4, hh = bh & 15;
    const int l0 = blockIdx.y * 128;

    {
        const int r4 = tid * 4;
        float4 am = *(const float4*)(amask + b * 1024 + r4);
        int4 sk = *(const int4*)(skim + b * 1024 + r4);
        Lg[r4 + 0] = __expf(am.x) * (float)sk.x;
        Lg[r4 + 1] = __expf(am.y) * (float)sk.y;
        Lg[r4 + 2] = __expf(am.z) * (float)sk.z;
        Lg[r4 + 3] = __expf(am.w) * (float)sk.w;
    }
    __syncthreads();

    const short* Qg = Qf + (size_t)bh * 65536;
    const short* Kg = Kf + (size_t)bh * 65536;
    const short* Vg = Vt + (size_t)bh * 65536;

    // Q B-frags (pre-scaled by log2e/8)
    bfrag qa[4];
#pragma unroll
    for (int c = 0; c < 4; c++)
        qa[c] = *(const bfrag*)(Qg + ((size_t)(((l0 >> 5) + w) * 4 + c) * 64 + lane) * 8);

    cfrag oacc[2];
#pragma unroll
    for (int mt = 0; mt < 2; mt++)
#pragma unroll
        for (int e = 0; e < 16; e++) oacc[mt][e] = 0.f;
    float es[4] = {0.f, 0.f, 0.f, 0.f};

    const int Lband = l0 + 32 * w;          // wave's first l-column
    const int lg = Lband + l31;             // this lane's l-column
    const int rowb = (32 * w + l31) * 132;  // private ring row (shorts)

    // ---- pipeline helpers ----
    auto LOADPB = [&](int r0k, bfrag (&PB)[2][4]) {   // PE rows for PRODUCE(r0k)
#pragma unroll
        for (int mt = 0; mt < 2; mt++) {
            const int er = min(max(Lband - r0k - 128 + 32 * mt + l31 + 1023, 0), 2046);
#pragma unroll
            for (int kc = 0; kc < 4; kc++)
                PB[mt][kc] = *(const bfrag*)(Db + (size_t)er * 64 + kc * 16 + q2 * 8);
        }
    };
    auto PRODUCE = [&](int r0k, bfrag (&PB)[2][4]) {  // fills window [r0k+64,+128)
#pragma unroll
        for (int mt = 0; mt < 2; mt++) {
            cfrag t;
#pragma unroll
            for (int e = 0; e < 16; e++) t[e] = 0.f;
            __builtin_amdgcn_s_setprio(1);
#pragma unroll
            for (int kc = 0; kc < 4; kc++)
                t = __builtin_amdgcn_mfma_f32_32x32x16_bf16(PB[mt][kc], qa[kc], t, 0, 0, 0);
            __builtin_amdgcn_s_setprio(0);
#pragma unroll
            for (int e = 0; e < 16; e++) {
                const int rr = (e & 3) + 8 * (e >> 2) + 4 * q2;
                Tb[rowb + ((l31 + r0k - 32 * mt - rr) & 127)] = f2bf(t[e]);
            }
        }
    };
    auto LOADKB = [&](int r0k, bfrag (&KB)[2][4]) {
#pragma unroll
        for (int mt = 0; mt < 2; mt++)
#pragma unroll
            for (int kc = 0; kc < 4; kc++)
                KB[mt][kc] = *(const bfrag*)(Kg
                    + ((size_t)(((r0k >> 5) + mt) * 4 + kc) * 64 + lane) * 8);
    };
    auto LOADTR = [&](int r0k, v2i (&TR)[8]) {
#pragma unroll
        for (int i = 0; i < 8; i++)
            TR[i] = *(const v2i*)&Tb[rowb
                + ((r0k + 32 * (i >> 2) + 8 * (i & 3) + 4 * q2) & 127)];
    };
    auto CONSUME = [&](int r0v, bfrag (&KB)[2][4], v2i (&TR)[8]) {
#pragma unroll
        for (int mt = 0; mt < 2; mt++) {
            bfrag vbl[2][2];   // V frags for this mt's two k-chunks
#pragma unroll
            for (int c = 0; c < 2; c++)
#pragma unroll
                for (int mtd = 0; mtd < 2; mtd++)
                    vbl[c][mtd] = *(const bfrag*)(Vg
                        + ((size_t)(mtd * 64 + (r0v >> 4) + 2 * mt + c) * 64 + lane) * 8);
            cfrag sfr;
#pragma unroll
            for (int e = 0; e < 16; e++) sfr[e] = 0.f;
            __builtin_amdgcn_s_setprio(1);
#pragma unroll
            for (int kc = 0; kc < 4; kc++)
                sfr = __builtin_amdgcn_mfma_f32_32x32x16_bf16(
                    KB[mt][kc], qa[kc], sfr, 0, 0, 0);
            __builtin_amdgcn_s_setprio(0);

            unsigned int P[4][2];
#pragma unroll
            for (int g = 0; g < 4; g++) {
                const int rb = r0v + 32 * mt + 8 * g + 4 * q2;
                float4 g4 = *(const float4*)&Lg[rb];
                v2i tr2 = TR[4 * mt + g];
                const float tv0 = __builtin_bit_cast(float, (unsigned)tr2[0] << 16);
                const float tv1 = __builtin_bit_cast(float, (unsigned)tr2[0] & 0xffff0000u);
                const float tv2 = __builtin_bit_cast(float, (unsigned)tr2[1] << 16);
                const float tv3 = __builtin_bit_cast(float, (unsigned)tr2[1] & 0xffff0000u);
                float ev0 = __builtin_amdgcn_exp2f(sfr[4 * g + 0] + tv0) * g4.x;
                float ev1 = __builtin_amdgcn_exp2f(sfr[4 * g + 1] + tv1) * g4.y;
                float ev2 = __builtin_amdgcn_exp2f(sfr[4 * g + 2] + tv2) * g4.z;
                float ev3 = __builtin_amdgcn_exp2f(sfr[4 * g + 3] + tv3) * g4.w;
                es[0] += ev0; es[1] += ev1; es[2] += ev2; es[3] += ev3;
                P[g][0] = pk2(f2bf(ev0), f2bf(ev1));
                P[g][1] = pk2(f2bf(ev2), f2bf(ev3));
            }
#pragma unroll
            for (int c = 0; c < 2; c++) {
                v2i s0 = __builtin_amdgcn_permlane32_swap(
                    (int)P[2 * c][0], (int)P[2 * c + 1][0], false, false);
                v2i s1 = __builtin_amdgcn_permlane32_swap(
                    (int)P[2 * c][1], (int)P[2 * c + 1][1], false, false);
                union { bfrag f; int d[4]; } u;
                u.d[0] = s0[0]; u.d[1] = s1[0]; u.d[2] = s0[1]; u.d[3] = s1[1];
                __builtin_amdgcn_s_setprio(1);
#pragma unroll
                for (int mtd = 0; mtd < 2; mtd++)
                    oacc[mtd] = __builtin_amdgcn_mfma_f32_32x32x16_bf16(
                        vbl[c][mtd], u.f, oacc[mtd], 0, 0, 0);
                __builtin_amdgcn_s_setprio(0);
            }
        }
    };

    bfrag kbA[2][4], kbB[2][4], pb[2][4];
    v2i trA[8], trB[8];

    // ---- prologue: two productions fill slots [0,64) incl. stragglers ----
    LOADPB(-128, pb);
    LOADKB(0, kbA);
    PRODUCE(-128, pb);
    LOADPB(-64, pb);
    PRODUCE(-64, pb);
    LOADTR(0, trA);
    LOADPB(0, pb);

    for (int r0 = 0; r0 < 1024; r0 += 128) {
        // body A: consume r0
        LOADKB(r0 + 64, kbB);
        CONSUME(r0, kbA, trA);
        PRODUCE(r0, pb);              // window [r0+64,+128)
        LOADTR(r0 + 64, trB);
        LOADPB(r0 + 64, pb);
        // body B: consume r0+64
        if (r0 + 128 < 1024) LOADKB(r0 + 128, kbA);
        CONSUME(r0 + 64, kbB, trB);
        if (r0 + 64 < 960) {
            PRODUCE(r0 + 64, pb);     // window [r0+128,+192)
            LOADTR(r0 + 128, trA);
            LOADPB(r0 + 128, pb);
        }
    }

    // ---- finalize ----
    float esum = (es[0] + es[1]) + (es[2] + es[3]);
    const float den = EPSV + esum + __shfl_xor(esum, 32);
    const float inv = 1.0f / den;
    float* ob = out + ((size_t)(b * 1024 + lg) * 1024) + hh * 64;
#pragma unroll
    for (int mtd = 0; mtd < 2; mtd++) {
#pragma unroll
        for (int g = 0; g < 4; g++) {
            float4 o;
            o.x = oacc[mtd][4 * g + 0] * inv;
            o.y = oacc[mtd][4 * g + 1] * inv;
            o.z = oacc[mtd][4 * g + 2] * inv;
            o.w = oacc[mtd][4 * g + 3] * inv;
            *(float4*)(ob + 32 * mtd + 8 * g + 4 * q2) = o;
        }
    }
}

// ---------------------------------------------------------------------------
extern "C" void kernel_launch(void* const* d_in, const int* in_sizes, int n_in,
                              void* d_out, int out_size, void* d_ws, size_t ws_size,
                              hipStream_t stream) {
    const float* hidden = (const float*)d_in[0];
    const float* amask  = (const float*)d_in[1];
    const int*   skim   = (const int*)d_in[2];
    const float* Wq     = (const float*)d_in[3];
    const float* bq     = (const float*)d_in[4];
    const float* Wk     = (const float*)d_in[5];
    const float* bk     = (const float*)d_in[6];
    const float* Wv     = (const float*)d_in[7];
    const float* bv     = (const float*)d_in[8];
    const float* dist   = (const float*)d_in[9];
    float* out = (float*)d_out;

    char* w = (char*)d_ws;
    short* Xs  = (short*)(w);                        // 8 MB frag-major X
    short* Wt  = (short*)(w + ((size_t)8 << 20));    // 6 MB frag-major W^T
    short* Db  = (short*)(w + ((size_t)14 << 20));   // 0.25 MB dist bf16
    short* Qf  = (short*)(w + ((size_t)15 << 20));   // 8 MB frag-major Q
    short* Kf  = (short*)(w + ((size_t)23 << 20));   // 8 MB frag-major K
    short* Vt  = (short*)(w + ((size_t)31 << 20));   // 8 MB frag-major V^T

    prep<<<3648, 256, 0, stream>>>(hidden, Wq, Wk, Wv, dist, Xs, Wt, Db);
    qkv_mfma<<<dim3(32, 8, 3), 256, 0, stream>>>(Xs, Wt, bq, bk, bv, Qf, Kf, Vt);
    attn_mfma<<<dim3(64, 8), 256, 0, stream>>>(Qf, Kf, Vt, Db, amask, skim, out);
}

// Round 7
// 187.105 us; speedup vs baseline: 1.2499x; 1.2499x over previous
//
#include <hip/hip_runtime.h>
#include <hip/hip_bf16.h>

// BertSelfAttention B=4,S=1024,HID=1024,H=16,D=64,MAXP=1024 — Round 14.
// R13 post-mortem: NaN output. Bundled 3 novel mechanisms; audit clears the
// C-operand fold (index/math-identical to R11's post-add) and v2f packing;
// prime suspect = inline-asm v_cvt_pk_bf16_f32 (if dst packing != {lo=src0,
// hi=src1}, garbage bf16 -> ring -> exp2 -> inf -> inf*0 = NaN; exactly the
// observed mode). m240 also says hand-written cvt_pk is SLOWER than scalar
// casts (compiler auto-fuses f2bf pairs into cvt_pk). R14 = R13 minus all
// cvtpk (back to f2bf/pk2), keeping: Toeplitz->MFMA-C fold, packed v2f es
// accum, hoisted trr/kb/vbl, setprio, qkv reg-dbuf (R12-verified).
// Spill alarm: WRITE_SIZE > 17MB.
// ws: Xs[0,8M) Wt[8M,14M) Db[14M,14.25M) Qf[15M) Kf[23M) Vt[31M)

#define EPSV 1e-8f

typedef short bfrag __attribute__((ext_vector_type(8)));   // 8 bf16
typedef float cfrag __attribute__((ext_vector_type(16)));  // C/D 32x32
typedef int v2i __attribute__((ext_vector_type(2)));
typedef float v2f __attribute__((ext_vector_type(2)));

__device__ __forceinline__ short f2bf(float f) {
    __hip_bfloat16 h = __float2bfloat16(f);
    return *reinterpret_cast<short*>(&h);
}
__device__ __forceinline__ unsigned int pk2(short a, short b) {
    return (unsigned int)(unsigned short)a | ((unsigned int)(unsigned short)b << 16);
}

// ---------------------------------------------------------------------------
// prep: fused cvt/swizzle. grid.x = 3648, 256 thr.
__global__ __launch_bounds__(256) void prep(
    const float* __restrict__ hidden, const float* __restrict__ Wq,
    const float* __restrict__ Wk, const float* __restrict__ Wv,
    const float* __restrict__ dist,
    short* __restrict__ Xs, short* __restrict__ Wt, short* __restrict__ Db)
{
    __shared__ short Tl[32 * 72];
    const int bid = blockIdx.x, tid = threadIdx.x;

    if (bid < 2048) {                      // X: 128 m-tiles x 16 k-groups
        const int mt = bid >> 4, kg = bid & 15;
        const int m_l = tid >> 3, k8 = (tid & 7) * 8;
        const float* src = hidden + (size_t)(mt * 32 + m_l) * 1024 + kg * 64 + k8;
        float4 v0 = *(const float4*)src, v1 = *(const float4*)(src + 4);
        short o[8];
        o[0] = f2bf(v0.x); o[1] = f2bf(v0.y); o[2] = f2bf(v0.z); o[3] = f2bf(v0.w);
        o[4] = f2bf(v1.x); o[5] = f2bf(v1.y); o[6] = f2bf(v1.z); o[7] = f2bf(v1.w);
        *(bfrag*)&Tl[m_l * 72 + k8] = *(bfrag*)o;
        __syncthreads();
        const int l31 = tid & 31, q2 = (tid >> 5) & 1, kc = tid >> 6;
        bfrag r = *(const bfrag*)&Tl[l31 * 72 + kc * 16 + q2 * 8];
        *(bfrag*)(Xs + ((size_t)(mt * 64 + kg * 4 + kc) * 64 + q2 * 32 + l31) * 8) = r;
    } else if (bid < 3584) {               // W: 3 z x 32 n-tiles x 16 k-groups
        const int t = bid - 2048, z = t >> 9, nt = (t >> 4) & 31, kg = t & 15;
        const float* W = (z == 0) ? Wq : ((z == 1) ? Wk : Wv);
        const int k_l = tid >> 2, n8 = (tid & 3) * 8;
        const float* src = W + (size_t)(kg * 64 + k_l) * 1024 + nt * 32 + n8;
        float4 v0 = *(const float4*)src, v1 = *(const float4*)(src + 4);
        float vv[8] = {v0.x, v0.y, v0.z, v0.w, v1.x, v1.y, v1.z, v1.w};
#pragma unroll
        for (int i = 0; i < 8; i++)
            Tl[(n8 + i) * 72 + k_l] = f2bf(vv[i]);   // transpose into LDS
        __syncthreads();
        const int l31 = tid & 31, q2 = (tid >> 5) & 1, kc = tid >> 6;
        bfrag r = *(const bfrag*)&Tl[l31 * 72 + kc * 16 + q2 * 8];
        *(bfrag*)(Wt + (size_t)z * 1048576
                  + ((size_t)(nt * 64 + kg * 4 + kc) * 64 + q2 * 32 + l31) * 8) = r;
    } else {                               // dist: 2047*64 = 131008 elems
        const int idx = (bid - 3584) * 256 + tid;
        if (idx < 16376) {
            const float* src = dist + (size_t)idx * 8;
            float4 v0 = *(const float4*)src, v1 = *(const float4*)(src + 4);
            short o[8];
            o[0] = f2bf(v0.x); o[1] = f2bf(v0.y); o[2] = f2bf(v0.z); o[3] = f2bf(v0.w);
            o[4] = f2bf(v1.x); o[5] = f2bf(v1.y); o[6] = f2bf(v1.z); o[7] = f2bf(v1.w);
            *(bfrag*)(Db + (size_t)idx * 8) = *(bfrag*)o;
        }
    }
}

// ---------------------------------------------------------------------------
// QKV GEMM, LDS-free. 128x128 block, 4 waves 2x2 of 64x64.
// K-loop explicitly double-buffered (load group k+1 while MFMA group k).
__global__ __launch_bounds__(256) void qkv_mfma(
    const short* __restrict__ Xs, const short* __restrict__ Wt,
    const float* __restrict__ bq, const float* __restrict__ bk,
    const float* __restrict__ bv,
    short* __restrict__ Qf, short* __restrict__ Kf, short* __restrict__ Vt)
{
    const int z = blockIdx.z;
    const short* W = Wt + (size_t)z * 1048576;
    const float* bias = (z == 0) ? bq : ((z == 1) ? bk : bv);
    // fold 1/sqrt(D) AND log2(e) into Q: 0.125 * 1.4426950408889634
    const float scale = (z == 0) ? 0.18033688011112042f : 1.0f;

    const int tid = threadIdx.x, lane = tid & 63, wid = tid >> 6;
    const int q2 = lane >> 5, l31 = lane & 31;
    const int wr = wid >> 1, wc = wid & 1;
    const int m0 = blockIdx.x * 128, n0 = blockIdx.y * 128;

    cfrag acc[2][2];
#pragma unroll
    for (int i = 0; i < 2; i++)
#pragma unroll
        for (int j = 0; j < 2; j++)
#pragma unroll
            for (int e = 0; e < 16; e++) acc[i][j][e] = 0.f;

    const short* ap0 = Xs + ((size_t)((m0 >> 5) + wr * 2 + 0) * 64 * 64 + lane) * 8;
    const short* ap1 = Xs + ((size_t)((m0 >> 5) + wr * 2 + 1) * 64 * 64 + lane) * 8;
    const short* bp0 = W  + ((size_t)((n0 >> 5) + wc * 2 + 0) * 64 * 64 + lane) * 8;
    const short* bp1 = W  + ((size_t)((n0 >> 5) + wc * 2 + 1) * 64 * 64 + lane) * 8;

    bfrag a0c, a1c, b0c, b1c, a0n, a1n, b0n, b1n;
    a0c = *(const bfrag*)(ap0); a1c = *(const bfrag*)(ap1);
    b0c = *(const bfrag*)(bp0); b1c = *(const bfrag*)(bp1);

#pragma unroll 2
    for (int kc = 0; kc < 64; kc += 2) {
        {   // prefetch group kc+1
            const int off = (kc + 1) * 512;
            a0n = *(const bfrag*)(ap0 + off); a1n = *(const bfrag*)(ap1 + off);
            b0n = *(const bfrag*)(bp0 + off); b1n = *(const bfrag*)(bp1 + off);
        }
        acc[0][0] = __builtin_amdgcn_mfma_f32_32x32x16_bf16(a0c, b0c, acc[0][0], 0, 0, 0);
        acc[0][1] = __builtin_amdgcn_mfma_f32_32x32x16_bf16(a0c, b1c, acc[0][1], 0, 0, 0);
        acc[1][0] = __builtin_amdgcn_mfma_f32_32x32x16_bf16(a1c, b0c, acc[1][0], 0, 0, 0);
        acc[1][1] = __builtin_amdgcn_mfma_f32_32x32x16_bf16(a1c, b1c, acc[1][1], 0, 0, 0);
        if (kc + 2 < 64) {   // prefetch group kc+2
            const int off = (kc + 2) * 512;
            a0c = *(const bfrag*)(ap0 + off); a1c = *(const bfrag*)(ap1 + off);
            b0c = *(const bfrag*)(bp0 + off); b1c = *(const bfrag*)(bp1 + off);
        }
        acc[0][0] = __builtin_amdgcn_mfma_f32_32x32x16_bf16(a0n, b0n, acc[0][0], 0, 0, 0);
        acc[0][1] = __builtin_amdgcn_mfma_f32_32x32x16_bf16(a0n, b1n, acc[0][1], 0, 0, 0);
        acc[1][0] = __builtin_amdgcn_mfma_f32_32x32x16_bf16(a1n, b0n, acc[1][0], 0, 0, 0);
        acc[1][1] = __builtin_amdgcn_mfma_f32_32x32x16_bf16(a1n, b1n, acc[1][1], 0, 0, 0);
    }

    // epilogue: +bias, (Q: x scale), cvt bf16, scatter frag-major per bh
#pragma unroll
    for (int nt = 0; nt < 2; nt++) {
        const int c = n0 + wc * 64 + nt * 32 + l31;    // channel
        const float bval = bias[c];
        const int h = c >> 6;
        const int d = nt * 32 + l31;                   // c & 63
#pragma unroll
        for (int mt = 0; mt < 2; mt++) {
            const int tok0 = m0 + wr * 64 + mt * 32;
            const int bb = tok0 >> 10, s_base = tok0 & 1023;
            const size_t bhbase = (size_t)(bb * 16 + h) * 65536;
            if (z < 2) {
                short* outp = (z == 0) ? Qf : Kf;
                const size_t fbase = bhbase
                    + ((size_t)((s_base >> 5) * 4 + (d >> 4)) * 64
                       + ((d >> 3) & 1) * 32) * 8 + (d & 7);
#pragma unroll
                for (int reg = 0; reg < 16; reg++) {
                    const int row = (reg & 3) + 8 * (reg >> 2) + 4 * q2;
                    outp[fbase + (size_t)row * 8] = f2bf((acc[mt][nt][reg] + bval) * scale);
                }
            } else {
                // V^T frag-major: elem (d, s): ((d>>5)*64 + (s>>4))*64*8 ...
#pragma unroll
                for (int g = 0; g < 4; g++) {
                    const float e0 = acc[mt][nt][4 * g + 0] + bval;
                    const float e1 = acc[mt][nt][4 * g + 1] + bval;
                    const float e2 = acc[mt][nt][4 * g + 2] + bval;
                    const float e3 = acc[mt][nt][4 * g + 3] + bval;
                    uint2 w2;
                    w2.x = pk2(f2bf(e0), f2bf(e1));
                    w2.y = pk2(f2bf(e2), f2bf(e3));
                    const size_t flat = bhbase
                        + ((size_t)(nt * 64 + (s_base >> 4) + (g >> 1)) * 64
                           + (g & 1) * 32 + l31) * 8 + 4 * q2;
                    *(uint2*)(Vt + flat) = w2;
                }
            }
        }
    }
}

// ---------------------------------------------------------------------------
// Fused attention. grid (64 bh, 8 l-tiles), 256 thr (4 waves).
// Wave w owns l-cols [l0+32w, +32) for all r. Barrier-free main loop.
// Toeplitz ring indexed BY R: row l31 holds T(lg - r) at slot r&127.
// Production pipelined one iteration ahead. T enters scores as the MFMA
// C-operand (no post-MFMA add). bf16 packing via f2bf/pk2 (compiler fuses
// to v_cvt_pk_bf16_f32 itself; hand asm was R13's NaN suspect).
__global__ __launch_bounds__(256, 2) void attn_mfma(
    const short* __restrict__ Qf, const short* __restrict__ Kf,
    const short* __restrict__ Vt, const short* __restrict__ Db,
    const float* __restrict__ amask, const int* __restrict__ skim,
    float* __restrict__ out)
{
    __shared__ short Tb[128 * 132];   // per-(wave,lane) r-ring, stride 132
    __shared__ float Lg[1024];        // g[r] = exp(amask)*skim

    const int tid = threadIdx.x, lane = tid & 63, w = tid >> 6;
    const int q2 = lane >> 5, l31 = lane & 31;
    const int bh = blockIdx.x, b = bh >> 4, hh = bh & 15;
    const int l0 = blockIdx.y * 128;

    {
        const int r4 = tid * 4;
        float4 am = *(const float4*)(amask + b * 1024 + r4);
        int4 sk = *(const int4*)(skim + b * 1024 + r4);
        Lg[r4 + 0] = __expf(am.x) * (float)sk.x;
        Lg[r4 + 1] = __expf(am.y) * (float)sk.y;
        Lg[r4 + 2] = __expf(am.z) * (float)sk.z;
        Lg[r4 + 3] = __expf(am.w) * (float)sk.w;
    }
    __syncthreads();

    const short* Qg = Qf + (size_t)bh * 65536;
    const short* Kg = Kf + (size_t)bh * 65536;
    const short* Vg = Vt + (size_t)bh * 65536;

    // Q B-frags (pre-scaled by log2e/8)
    bfrag qa[4];
#pragma unroll
    for (int c = 0; c < 4; c++)
        qa[c] = *(const bfrag*)(Qg + ((size_t)(((l0 >> 5) + w) * 4 + c) * 64 + lane) * 8);

    cfrag oacc[2];
#pragma unroll
    for (int mt = 0; mt < 2; mt++)
#pragma unroll
        for (int e = 0; e < 16; e++) oacc[mt][e] = 0.f;
    v2f es01 = {0.f, 0.f}, es23 = {0.f, 0.f};

    const int Lband = l0 + 32 * w;          // wave's first l-column
    const int lg = Lband + l31;             // this lane's l-column
    const int rowb = (32 * w + l31) * 132;  // private ring row (shorts)

    for (int r0 = -128; r0 < 1024; r0 += 64) {
        const bool produce = r0 < 960;

        // ---- issue production's Db loads early (independent) ----
        bfrag pb[2][4];
        if (produce) {
#pragma unroll
            for (int mt = 0; mt < 2; mt++) {
                const int D0 = Lband - r0 - 128 + 32 * mt;   // dist block base
                const int er = min(max(D0 + l31 + 1023, 0), 2046);
#pragma unroll
                for (int kc = 0; kc < 4; kc++)
                    pb[mt][kc] = *(const bfrag*)(Db + (size_t)er * 64 + kc * 16 + q2 * 8);
            }
        }

        if (r0 >= 0) {
            // ---- K, V frag loads and ring reads, all hoisted ----
            bfrag kb[2][4], vbl[4][2];
            v2i trr[2][4];
#pragma unroll
            for (int mt = 0; mt < 2; mt++)
#pragma unroll
                for (int kc = 0; kc < 4; kc++)
                    kb[mt][kc] = *(const bfrag*)(Kg
                        + ((size_t)(((r0 >> 5) + mt) * 4 + kc) * 64 + lane) * 8);
#pragma unroll
            for (int kc = 0; kc < 4; kc++)
#pragma unroll
                for (int mtd = 0; mtd < 2; mtd++)
                    vbl[kc][mtd] = *(const bfrag*)(Vg
                        + ((size_t)(mtd * 64 + (r0 >> 4) + kc) * 64 + lane) * 8);
#pragma unroll
            for (int mt = 0; mt < 2; mt++)
#pragma unroll
                for (int g = 0; g < 4; g++)
                    trr[mt][g] = *(const v2i*)&Tb[rowb
                        + ((r0 + 32 * mt + 8 * g + 4 * q2) & 127)];

            // ---- per 32-r block: scores (C=T), softmax, relayout, PV ----
#pragma unroll
            for (int mt = 0; mt < 2; mt++) {
                cfrag sfr;
#pragma unroll
                for (int g = 0; g < 4; g++) {
                    const v2i t2 = trr[mt][g];
                    sfr[4 * g + 0] = __builtin_bit_cast(float, (unsigned)t2[0] << 16);
                    sfr[4 * g + 1] = __builtin_bit_cast(float, (unsigned)t2[0] & 0xffff0000u);
                    sfr[4 * g + 2] = __builtin_bit_cast(float, (unsigned)t2[1] << 16);
                    sfr[4 * g + 3] = __builtin_bit_cast(float, (unsigned)t2[1] & 0xffff0000u);
                }
                __builtin_amdgcn_s_setprio(1);
#pragma unroll
                for (int kc = 0; kc < 4; kc++)
                    sfr = __builtin_amdgcn_mfma_f32_32x32x16_bf16(
                        kb[mt][kc], qa[kc], sfr, 0, 0, 0);
                __builtin_amdgcn_s_setprio(0);

                unsigned int P[4][2];
#pragma unroll
                for (int g = 0; g < 4; g++) {
                    const int rb = r0 + 32 * mt + 8 * g + 4 * q2;
                    float4 g4 = *(const float4*)&Lg[rb];
                    float ev0 = __builtin_amdgcn_exp2f(sfr[4 * g + 0]) * g4.x;
                    float ev1 = __builtin_amdgcn_exp2f(sfr[4 * g + 1]) * g4.y;
                    float ev2 = __builtin_amdgcn_exp2f(sfr[4 * g + 2]) * g4.z;
                    float ev3 = __builtin_amdgcn_exp2f(sfr[4 * g + 3]) * g4.w;
                    es01 += (v2f){ev0, ev1};
                    es23 += (v2f){ev2, ev3};
                    P[g][0] = pk2(f2bf(ev0), f2bf(ev1));
                    P[g][1] = pk2(f2bf(ev2), f2bf(ev3));
                }
                // in-register relayout: score C-frag -> PV B-frag
#pragma unroll
                for (int c = 0; c < 2; c++) {
                    v2i s0 = __builtin_amdgcn_permlane32_swap(
                        (int)P[2 * c][0], (int)P[2 * c + 1][0], false, false);
                    v2i s1 = __builtin_amdgcn_permlane32_swap(
                        (int)P[2 * c][1], (int)P[2 * c + 1][1], false, false);
                    union { bfrag f; int d[4]; } u;
                    u.d[0] = s0[0]; u.d[1] = s1[0]; u.d[2] = s0[1]; u.d[3] = s1[1];
                    const int kc = 2 * mt + c;
                    __builtin_amdgcn_s_setprio(1);
#pragma unroll
                    for (int mtd = 0; mtd < 2; mtd++)
                        oacc[mtd] = __builtin_amdgcn_mfma_f32_32x32x16_bf16(
                            vbl[kc][mtd], u.f, oacc[mtd], 0, 0, 0);
                    __builtin_amdgcn_s_setprio(0);
                }
            }
        }

        // ---- production: T window for [r0+64, r0+127] (after gathers) ----
        if (produce) {
#pragma unroll
            for (int mt = 0; mt < 2; mt++) {
                cfrag t;
#pragma unroll
                for (int e = 0; e < 16; e++) t[e] = 0.f;
                __builtin_amdgcn_s_setprio(1);
#pragma unroll
                for (int kc = 0; kc < 4; kc++)
                    t = __builtin_amdgcn_mfma_f32_32x32x16_bf16(
                        pb[mt][kc], qa[kc], t, 0, 0, 0);
                __builtin_amdgcn_s_setprio(0);
#pragma unroll
                for (int e = 0; e < 16; e++) {
                    const int rr = (e & 3) + 8 * (e >> 2) + 4 * q2;
                    Tb[rowb + ((l31 + r0 - 32 * mt - rr) & 127)] = f2bf(t[e]);
                }
            }
        }
    }

    // ---- finalize ----
    float esum = (es01[0] + es01[1]) + (es23[0] + es23[1]);
    const float den = EPSV + esum + __shfl_xor(esum, 32);
    const float inv = 1.0f / den;
    float* ob = out + ((size_t)(b * 1024 + lg) * 1024) + hh * 64;
#pragma unroll
    for (int mtd = 0; mtd < 2; mtd++) {
#pragma unroll
        for (int g = 0; g < 4; g++) {
            float4 o;
            o.x = oacc[mtd][4 * g + 0] * inv;
            o.y = oacc[mtd][4 * g + 1] * inv;
            o.z = oacc[mtd][4 * g + 2] * inv;
            o.w = oacc[mtd][4 * g + 3] * inv;
            *(float4*)(ob + 32 * mtd + 8 * g + 4 * q2) = o;
        }
    }
}

// ---------------------------------------------------------------------------
extern "C" void kernel_launch(void* const* d_in, const int* in_sizes, int n_in,
                              void* d_out, int out_size, void* d_ws, size_t ws_size,
                              hipStream_t stream) {
    const float* hidden = (const float*)d_in[0];
    const float* amask  = (const float*)d_in[1];
    const int*   skim   = (const int*)d_in[2];
    const float* Wq     = (const float*)d_in[3];
    const float* bq     = (const float*)d_in[4];
    const float* Wk     = (const float*)d_in[5];
    const float* bk     = (const float*)d_in[6];
    const float* Wv     = (const float*)d_in[7];
    const float* bv     = (const float*)d_in[8];
    const float* dist   = (const float*)d_in[9];
    float* out = (float*)d_out;

    char* w = (char*)d_ws;
    short* Xs  = (short*)(w);                        // 8 MB frag-major X
    short* Wt  = (short*)(w + ((size_t)8 << 20));    // 6 MB frag-major W^T
    short* Db  = (short*)(w + ((size_t)14 << 20));   // 0.25 MB dist bf16
    short* Qf  = (short*)(w + ((size_t)15 << 20));   // 8 MB frag-major Q
    short* Kf  = (short*)(w + ((size_t)23 << 20));   // 8 MB frag-major K
    short* Vt  = (short*)(w + ((size_t)31 << 20));   // 8 MB frag-major V^T

    prep<<<3648, 256, 0, stream>>>(hidden, Wq, Wk, Wv, dist, Xs, Wt, Db);
    qkv_mfma<<<dim3(32, 8, 3), 256, 0, stream>>>(Xs, Wt, bq, bk, bv, Qf, Kf, Vt);
    attn_mfma<<<dim3(64, 8), 256, 0, stream>>>(Qf, Kf, Vt, Db, amask, skim, out);
}

// Round 8
// 186.200 us; speedup vs baseline: 1.2560x; 1.0049x over previous
//
#include <hip/hip_runtime.h>
#include <hip/hip_bf16.h>

// BertSelfAttention B=4,S=1024,HID=1024,H=16,D=64,MAXP=1024 — Round 15.
// R14 post-mortem: attn 62.2us best; 9.3k cy/iter vs ~700 cy issue work ->
// still wait-dominated. The only zero-cover load is kb (consumed by first
// MFMA each iter). R12 proved full multi-buffering spills at cap 128 under
// (256,2); R15 = R14 + kb-ONLY cross-iter double buffer, cap raised via
// amdgpu_waves_per_eu(2) (min 2 waves/EU -> 256 VGPR; grid pins occupancy
// at 2 blocks/CU anyway). vbl scoped per-mt (-16 liveness). qkv: prefetch
// depth 1 -> 4 (static rotation, 64%4==0, ~150 VGPR peak).
// Spill alarm: attn WRITE_SIZE > 17MB.
// ws: Xs[0,8M) Wt[8M,14M) Db[14M,14.25M) Qf[15M) Kf[23M) Vt[31M)

#define EPSV 1e-8f

typedef short bfrag __attribute__((ext_vector_type(8)));   // 8 bf16
typedef float cfrag __attribute__((ext_vector_type(16)));  // C/D 32x32
typedef int v2i __attribute__((ext_vector_type(2)));
typedef float v2f __attribute__((ext_vector_type(2)));

__device__ __forceinline__ short f2bf(float f) {
    __hip_bfloat16 h = __float2bfloat16(f);
    return *reinterpret_cast<short*>(&h);
}
__device__ __forceinline__ unsigned int pk2(short a, short b) {
    return (unsigned int)(unsigned short)a | ((unsigned int)(unsigned short)b << 16);
}

// ---------------------------------------------------------------------------
// prep: fused cvt/swizzle. grid.x = 3648, 256 thr.
__global__ __launch_bounds__(256) void prep(
    const float* __restrict__ hidden, const float* __restrict__ Wq,
    const float* __restrict__ Wk, const float* __restrict__ Wv,
    const float* __restrict__ dist,
    short* __restrict__ Xs, short* __restrict__ Wt, short* __restrict__ Db)
{
    __shared__ short Tl[32 * 72];
    const int bid = blockIdx.x, tid = threadIdx.x;

    if (bid < 2048) {                      // X: 128 m-tiles x 16 k-groups
        const int mt = bid >> 4, kg = bid & 15;
        const int m_l = tid >> 3, k8 = (tid & 7) * 8;
        const float* src = hidden + (size_t)(mt * 32 + m_l) * 1024 + kg * 64 + k8;
        float4 v0 = *(const float4*)src, v1 = *(const float4*)(src + 4);
        short o[8];
        o[0] = f2bf(v0.x); o[1] = f2bf(v0.y); o[2] = f2bf(v0.z); o[3] = f2bf(v0.w);
        o[4] = f2bf(v1.x); o[5] = f2bf(v1.y); o[6] = f2bf(v1.z); o[7] = f2bf(v1.w);
        *(bfrag*)&Tl[m_l * 72 + k8] = *(bfrag*)o;
        __syncthreads();
        const int l31 = tid & 31, q2 = (tid >> 5) & 1, kc = tid >> 6;
        bfrag r = *(const bfrag*)&Tl[l31 * 72 + kc * 16 + q2 * 8];
        *(bfrag*)(Xs + ((size_t)(mt * 64 + kg * 4 + kc) * 64 + q2 * 32 + l31) * 8) = r;
    } else if (bid < 3584) {               // W: 3 z x 32 n-tiles x 16 k-groups
        const int t = bid - 2048, z = t >> 9, nt = (t >> 4) & 31, kg = t & 15;
        const float* W = (z == 0) ? Wq : ((z == 1) ? Wk : Wv);
        const int k_l = tid >> 2, n8 = (tid & 3) * 8;
        const float* src = W + (size_t)(kg * 64 + k_l) * 1024 + nt * 32 + n8;
        float4 v0 = *(const float4*)src, v1 = *(const float4*)(src + 4);
        float vv[8] = {v0.x, v0.y, v0.z, v0.w, v1.x, v1.y, v1.z, v1.w};
#pragma unroll
        for (int i = 0; i < 8; i++)
            Tl[(n8 + i) * 72 + k_l] = f2bf(vv[i]);   // transpose into LDS
        __syncthreads();
        const int l31 = tid & 31, q2 = (tid >> 5) & 1, kc = tid >> 6;
        bfrag r = *(const bfrag*)&Tl[l31 * 72 + kc * 16 + q2 * 8];
        *(bfrag*)(Wt + (size_t)z * 1048576
                  + ((size_t)(nt * 64 + kg * 4 + kc) * 64 + q2 * 32 + l31) * 8) = r;
    } else {                               // dist: 2047*64 = 131008 elems
        const int idx = (bid - 3584) * 256 + tid;
        if (idx < 16376) {
            const float* src = dist + (size_t)idx * 8;
            float4 v0 = *(const float4*)src, v1 = *(const float4*)(src + 4);
            short o[8];
            o[0] = f2bf(v0.x); o[1] = f2bf(v0.y); o[2] = f2bf(v0.z); o[3] = f2bf(v0.w);
            o[4] = f2bf(v1.x); o[5] = f2bf(v1.y); o[6] = f2bf(v1.z); o[7] = f2bf(v1.w);
            *(bfrag*)(Db + (size_t)idx * 8) = *(bfrag*)o;
        }
    }
}

// ---------------------------------------------------------------------------
// QKV GEMM, LDS-free. 128x128 block, 4 waves 2x2 of 64x64.
// K-loop prefetch depth 4 (16 outstanding dwordx4; static rotation kc&3).
__global__ __launch_bounds__(256) void qkv_mfma(
    const short* __restrict__ Xs, const short* __restrict__ Wt,
    const float* __restrict__ bq, const float* __restrict__ bk,
    const float* __restrict__ bv,
    short* __restrict__ Qf, short* __restrict__ Kf, short* __restrict__ Vt)
{
    const int z = blockIdx.z;
    const short* W = Wt + (size_t)z * 1048576;
    const float* bias = (z == 0) ? bq : ((z == 1) ? bk : bv);
    // fold 1/sqrt(D) AND log2(e) into Q: 0.125 * 1.4426950408889634
    const float scale = (z == 0) ? 0.18033688011112042f : 1.0f;

    const int tid = threadIdx.x, lane = tid & 63, wid = tid >> 6;
    const int q2 = lane >> 5, l31 = lane & 31;
    const int wr = wid >> 1, wc = wid & 1;
    const int m0 = blockIdx.x * 128, n0 = blockIdx.y * 128;

    cfrag acc[2][2];
#pragma unroll
    for (int i = 0; i < 2; i++)
#pragma unroll
        for (int j = 0; j < 2; j++)
#pragma unroll
            for (int e = 0; e < 16; e++) acc[i][j][e] = 0.f;

    const short* ap0 = Xs + ((size_t)((m0 >> 5) + wr * 2 + 0) * 64 * 64 + lane) * 8;
    const short* ap1 = Xs + ((size_t)((m0 >> 5) + wr * 2 + 1) * 64 * 64 + lane) * 8;
    const short* bp0 = W  + ((size_t)((n0 >> 5) + wc * 2 + 0) * 64 * 64 + lane) * 8;
    const short* bp1 = W  + ((size_t)((n0 >> 5) + wc * 2 + 1) * 64 * 64 + lane) * 8;

    bfrag A0[4], A1[4], B0[4], B1[4];
#pragma unroll
    for (int g = 0; g < 4; g++) {          // prologue: 16 loads in flight
        const int off = g * 512;
        A0[g] = *(const bfrag*)(ap0 + off); A1[g] = *(const bfrag*)(ap1 + off);
        B0[g] = *(const bfrag*)(bp0 + off); B1[g] = *(const bfrag*)(bp1 + off);
    }

#pragma unroll 4
    for (int kc = 0; kc < 64; kc++) {
        const int s = kc & 3;              // static after unroll-4
        acc[0][0] = __builtin_amdgcn_mfma_f32_32x32x16_bf16(A0[s], B0[s], acc[0][0], 0, 0, 0);
        acc[0][1] = __builtin_amdgcn_mfma_f32_32x32x16_bf16(A0[s], B1[s], acc[0][1], 0, 0, 0);
        acc[1][0] = __builtin_amdgcn_mfma_f32_32x32x16_bf16(A1[s], B0[s], acc[1][0], 0, 0, 0);
        acc[1][1] = __builtin_amdgcn_mfma_f32_32x32x16_bf16(A1[s], B1[s], acc[1][1], 0, 0, 0);
        if (kc + 4 < 64) {                 // refill slot s for group kc+4
            const int off = (kc + 4) * 512;
            A0[s] = *(const bfrag*)(ap0 + off); A1[s] = *(const bfrag*)(ap1 + off);
            B0[s] = *(const bfrag*)(bp0 + off); B1[s] = *(const bfrag*)(bp1 + off);
        }
    }

    // epilogue: +bias, (Q: x scale), cvt bf16, scatter frag-major per bh
#pragma unroll
    for (int nt = 0; nt < 2; nt++) {
        const int c = n0 + wc * 64 + nt * 32 + l31;    // channel
        const float bval = bias[c];
        const int h = c >> 6;
        const int d = nt * 32 + l31;                   // c & 63
#pragma unroll
        for (int mt = 0; mt < 2; mt++) {
            const int tok0 = m0 + wr * 64 + mt * 32;
            const int bb = tok0 >> 10, s_base = tok0 & 1023;
            const size_t bhbase = (size_t)(bb * 16 + h) * 65536;
            if (z < 2) {
                short* outp = (z == 0) ? Qf : Kf;
                const size_t fbase = bhbase
                    + ((size_t)((s_base >> 5) * 4 + (d >> 4)) * 64
                       + ((d >> 3) & 1) * 32) * 8 + (d & 7);
#pragma unroll
                for (int reg = 0; reg < 16; reg++) {
                    const int row = (reg & 3) + 8 * (reg >> 2) + 4 * q2;
                    outp[fbase + (size_t)row * 8] = f2bf((acc[mt][nt][reg] + bval) * scale);
                }
            } else {
                // V^T frag-major: elem (d, s): ((d>>5)*64 + (s>>4))*64*8 ...
#pragma unroll
                for (int g = 0; g < 4; g++) {
                    const float e0 = acc[mt][nt][4 * g + 0] + bval;
                    const float e1 = acc[mt][nt][4 * g + 1] + bval;
                    const float e2 = acc[mt][nt][4 * g + 2] + bval;
                    const float e3 = acc[mt][nt][4 * g + 3] + bval;
                    uint2 w2;
                    w2.x = pk2(f2bf(e0), f2bf(e1));
                    w2.y = pk2(f2bf(e2), f2bf(e3));
                    const size_t flat = bhbase
                        + ((size_t)(nt * 64 + (s_base >> 4) + (g >> 1)) * 64
                           + (g & 1) * 32 + l31) * 8 + 4 * q2;
                    *(uint2*)(Vt + flat) = w2;
                }
            }
        }
    }
}

// ---------------------------------------------------------------------------
// Fused attention. grid (64 bh, 8 l-tiles), 256 thr (4 waves).
// Wave w owns l-cols [l0+32w, +32) for all r. Barrier-free main loop.
// Toeplitz ring indexed BY R: row l31 holds T(lg - r) at slot r&127.
// kb cross-iteration double-buffered (the one zero-cover load in R14);
// pb/vbl/trr single-buffered (already covered). 2-body unrolled main loop.
__global__ __launch_bounds__(256) __attribute__((amdgpu_waves_per_eu(2)))
void attn_mfma(
    const short* __restrict__ Qf, const short* __restrict__ Kf,
    const short* __restrict__ Vt, const short* __restrict__ Db,
    const float* __restrict__ amask, const int* __restrict__ skim,
    float* __restrict__ out)
{
    __shared__ short Tb[128 * 132];   // per-(wave,lane) r-ring, stride 132
    __shared__ float Lg[1024];        // g[r] = exp(amask)*skim

    const int tid = threadIdx.x, lane = tid & 63, w = tid >> 6;
    const int q2 = lane >> 5, l31 = lane & 31;
    const int bh = blockIdx.x, b = bh >> 4, hh = bh & 15;
    const int l0 = blockIdx.y * 128;

    {
        const int r4 = tid * 4;
        float4 am = *(const float4*)(amask + b * 1024 + r4);
        int4 sk = *(const int4*)(skim + b * 1024 + r4);
        Lg[r4 + 0] = __expf(am.x) * (float)sk.x;
        Lg[r4 + 1] = __expf(am.y) * (float)sk.y;
        Lg[r4 + 2] = __expf(am.z) * (float)sk.z;
        Lg[r4 + 3] = __expf(am.w) * (float)sk.w;
    }
    __syncthreads();

    const short* Qg = Qf + (size_t)bh * 65536;
    const short* Kg = Kf + (size_t)bh * 65536;
    const short* Vg = Vt + (size_t)bh * 65536;

    // Q B-frags (pre-scaled by log2e/8)
    bfrag qa[4];
#pragma unroll
    for (int c = 0; c < 4; c++)
        qa[c] = *(const bfrag*)(Qg + ((size_t)(((l0 >> 5) + w) * 4 + c) * 64 + lane) * 8);

    cfrag oacc[2];
#pragma unroll
    for (int mt = 0; mt < 2; mt++)
#pragma unroll
        for (int e = 0; e < 16; e++) oacc[mt][e] = 0.f;
    v2f es01 = {0.f, 0.f}, es23 = {0.f, 0.f};

    const int Lband = l0 + 32 * w;          // wave's first l-column
    const int lg = Lband + l31;             // this lane's l-column
    const int rowb = (32 * w + l31) * 132;  // private ring row (shorts)

    auto LOADPB = [&](int r0k, bfrag (&PB)[2][4]) {   // PE rows for PRODUCE(r0k)
#pragma unroll
        for (int mt = 0; mt < 2; mt++) {
            const int er = min(max(Lband - r0k - 128 + 32 * mt + l31 + 1023, 0), 2046);
#pragma unroll
            for (int kc = 0; kc < 4; kc++)
                PB[mt][kc] = *(const bfrag*)(Db + (size_t)er * 64 + kc * 16 + q2 * 8);
        }
    };
    auto PRODUCE = [&](int r0k, bfrag (&PB)[2][4]) {  // fills window [r0k+64,+128)
#pragma unroll
        for (int mt = 0; mt < 2; mt++) {
            cfrag t;
#pragma unroll
            for (int e = 0; e < 16; e++) t[e] = 0.f;
            __builtin_amdgcn_s_setprio(1);
#pragma unroll
            for (int kc = 0; kc < 4; kc++)
                t = __builtin_amdgcn_mfma_f32_32x32x16_bf16(PB[mt][kc], qa[kc], t, 0, 0, 0);
            __builtin_amdgcn_s_setprio(0);
#pragma unroll
            for (int e = 0; e < 16; e++) {
                const int rr = (e & 3) + 8 * (e >> 2) + 4 * q2;
                Tb[rowb + ((l31 + r0k - 32 * mt - rr) & 127)] = f2bf(t[e]);
            }
        }
    };
    auto LOADKB = [&](int rk, bfrag (&KB)[2][4]) {
#pragma unroll
        for (int mt = 0; mt < 2; mt++)
#pragma unroll
            for (int kc = 0; kc < 4; kc++)
                KB[mt][kc] = *(const bfrag*)(Kg
                    + ((size_t)(((rk >> 5) + mt) * 4 + kc) * 64 + lane) * 8);
    };

    bfrag kbA[2][4], kbB[2][4];

    // BODY: consume r with CUR, prefetch kb(r+64) into NXT, produce(r).
    auto BODY = [&](int r, bfrag (&CUR)[2][4], bfrag (&NXT)[2][4]) {
        const bool prod = r < 960;
        bfrag pb[2][4];
        if (prod) LOADPB(r, pb);                  // for produce at body end
        if (r + 64 < 1024) LOADKB(r + 64, NXT);   // next body's scores
        v2i trr[2][4];
#pragma unroll
        for (int mt = 0; mt < 2; mt++)
#pragma unroll
            for (int g = 0; g < 4; g++)
                trr[mt][g] = *(const v2i*)&Tb[rowb
                    + ((r + 32 * mt + 8 * g + 4 * q2) & 127)];

#pragma unroll
        for (int mt = 0; mt < 2; mt++) {
            bfrag vbl[2][2];                      // per-mt V frags
#pragma unroll
            for (int c = 0; c < 2; c++)
#pragma unroll
                for (int mtd = 0; mtd < 2; mtd++)
                    vbl[c][mtd] = *(const bfrag*)(Vg
                        + ((size_t)(mtd * 64 + (r >> 4) + 2 * mt + c) * 64 + lane) * 8);

            cfrag sfr;                            // C-operand = Toeplitz T
#pragma unroll
            for (int g = 0; g < 4; g++) {
                const v2i t2 = trr[mt][g];
                sfr[4 * g + 0] = __builtin_bit_cast(float, (unsigned)t2[0] << 16);
                sfr[4 * g + 1] = __builtin_bit_cast(float, (unsigned)t2[0] & 0xffff0000u);
                sfr[4 * g + 2] = __builtin_bit_cast(float, (unsigned)t2[1] << 16);
                sfr[4 * g + 3] = __builtin_bit_cast(float, (unsigned)t2[1] & 0xffff0000u);
            }
            __builtin_amdgcn_s_setprio(1);
#pragma unroll
            for (int kc = 0; kc < 4; kc++)
                sfr = __builtin_amdgcn_mfma_f32_32x32x16_bf16(
                    CUR[mt][kc], qa[kc], sfr, 0, 0, 0);
            __builtin_amdgcn_s_setprio(0);

            unsigned int P[4][2];
#pragma unroll
            for (int g = 0; g < 4; g++) {
                const int rb = r + 32 * mt + 8 * g + 4 * q2;
                float4 g4 = *(const float4*)&Lg[rb];
                float ev0 = __builtin_amdgcn_exp2f(sfr[4 * g + 0]) * g4.x;
                float ev1 = __builtin_amdgcn_exp2f(sfr[4 * g + 1]) * g4.y;
                float ev2 = __builtin_amdgcn_exp2f(sfr[4 * g + 2]) * g4.z;
                float ev3 = __builtin_amdgcn_exp2f(sfr[4 * g + 3]) * g4.w;
                es01 += (v2f){ev0, ev1};
                es23 += (v2f){ev2, ev3};
                P[g][0] = pk2(f2bf(ev0), f2bf(ev1));
                P[g][1] = pk2(f2bf(ev2), f2bf(ev3));
            }
#pragma unroll
            for (int c = 0; c < 2; c++) {
                v2i s0 = __builtin_amdgcn_permlane32_swap(
                    (int)P[2 * c][0], (int)P[2 * c + 1][0], false, false);
                v2i s1 = __builtin_amdgcn_permlane32_swap(
                    (int)P[2 * c][1], (int)P[2 * c + 1][1], false, false);
                union { bfrag f; int d[4]; } u;
                u.d[0] = s0[0]; u.d[1] = s1[0]; u.d[2] = s0[1]; u.d[3] = s1[1];
                __builtin_amdgcn_s_setprio(1);
#pragma unroll
                for (int mtd = 0; mtd < 2; mtd++)
                    oacc[mtd] = __builtin_amdgcn_mfma_f32_32x32x16_bf16(
                        vbl[c][mtd], u.f, oacc[mtd], 0, 0, 0);
                __builtin_amdgcn_s_setprio(0);
            }
        }

        if (prod) PRODUCE(r, pb);
    };

    // ---- prologue: kb(0) issued first; two produces fill slots [0,64) ----
    {
        bfrag pb[2][4];
        LOADPB(-128, pb);
        LOADKB(0, kbA);
        PRODUCE(-128, pb);
        LOADPB(-64, pb);
        PRODUCE(-64, pb);
    }

    for (int r0 = 0; r0 < 1024; r0 += 128) {
        BODY(r0, kbA, kbB);
        BODY(r0 + 64, kbB, kbA);
    }

    // ---- finalize ----
    float esum = (es01[0] + es01[1]) + (es23[0] + es23[1]);
    const float den = EPSV + esum + __shfl_xor(esum, 32);
    const float inv = 1.0f / den;
    float* ob = out + ((size_t)(b * 1024 + lg) * 1024) + hh * 64;
#pragma unroll
    for (int mtd = 0; mtd < 2; mtd++) {
#pragma unroll
        for (int g = 0; g < 4; g++) {
            float4 o;
            o.x = oacc[mtd][4 * g + 0] * inv;
            o.y = oacc[mtd][4 * g + 1] * inv;
            o.z = oacc[mtd][4 * g + 2] * inv;
            o.w = oacc[mtd][4 * g + 3] * inv;
            *(float4*)(ob + 32 * mtd + 8 * g + 4 * q2) = o;
        }
    }
}

// ---------------------------------------------------------------------------
extern "C" void kernel_launch(void* const* d_in, const int* in_sizes, int n_in,
                              void* d_out, int out_size, void* d_ws, size_t ws_size,
                              hipStream_t stream) {
    const float* hidden = (const float*)d_in[0];
    const float* amask  = (const float*)d_in[1];
    const int*   skim   = (const int*)d_in[2];
    const float* Wq     = (const float*)d_in[3];
    const float* bq     = (const float*)d_in[4];
    const float* Wk     = (const float*)d_in[5];
    const float* bk     = (const float*)d_in[6];
    const float* Wv     = (const float*)d_in[7];
    const float* bv     = (const float*)d_in[8];
    const float* dist   = (const float*)d_in[9];
    float* out = (float*)d_out;

    char* w = (char*)d_ws;
    short* Xs  = (short*)(w);                        // 8 MB frag-major X
    short* Wt  = (short*)(w + ((size_t)8 << 20));    // 6 MB frag-major W^T
    short* Db  = (short*)(w + ((size_t)14 << 20));   // 0.25 MB dist bf16
    short* Qf  = (short*)(w + ((size_t)15 << 20));   // 8 MB frag-major Q
    short* Kf  = (short*)(w + ((size_t)23 << 20));   // 8 MB frag-major K
    short* Vt  = (short*)(w + ((size_t)31 << 20));   // 8 MB frag-major V^T

    prep<<<3648, 256, 0, stream>>>(hidden, Wq, Wk, Wv, dist, Xs, Wt, Db);
    qkv_mfma<<<dim3(32, 8, 3), 256, 0, stream>>>(Xs, Wt, bq, bk, bv, Qf, Kf, Vt);
    attn_mfma<<<dim3(64, 8), 256, 0, stream>>>(Qf, Kf, Vt, Db, amask, skim, out);
}

// Round 9
// 185.925 us; speedup vs baseline: 1.2578x; 1.0015x over previous
//
#include <hip/hip_runtime.h>
#include <hip/hip_bf16.h>

// BertSelfAttention B=4,S=1024,HID=1024,H=16,D=64,MAXP=1024 — Round 16.
// R15 post-mortem: kb dbuf pushed attn past the ~100-VGPR liveness cliff
// (VGPR capped 128, WRITE 16.9MB = ~0.5MB spill, attn 62.2->67.4). qkv
// depth-4 prefetch verified (total-attn 124.9->118.8). Third data point:
// every cross-iter buffer so far costs more in allocator pressure than it
// buys in latency cover.
// R16 = consolidation: attn = R14 verbatim (62.2us, VGPR 100, no spill);
// qkv/prep = R15 verbatim (depth-4). Establishes ~181us baseline; also
// checks cross-kernel codegen coupling (attn should repeat 62.2 +-0.5).
// Spill alarm: attn WRITE_SIZE > 17MB.
// ws: Xs[0,8M) Wt[8M,14M) Db[14M,14.25M) Qf[15M) Kf[23M) Vt[31M)

#define EPSV 1e-8f

typedef short bfrag __attribute__((ext_vector_type(8)));   // 8 bf16
typedef float cfrag __attribute__((ext_vector_type(16)));  // C/D 32x32
typedef int v2i __attribute__((ext_vector_type(2)));
typedef float v2f __attribute__((ext_vector_type(2)));

__device__ __forceinline__ short f2bf(float f) {
    __hip_bfloat16 h = __float2bfloat16(f);
    return *reinterpret_cast<short*>(&h);
}
__device__ __forceinline__ unsigned int pk2(short a, short b) {
    return (unsigned int)(unsigned short)a | ((unsigned int)(unsigned short)b << 16);
}

// ---------------------------------------------------------------------------
// prep: fused cvt/swizzle. grid.x = 3648, 256 thr.
__global__ __launch_bounds__(256) void prep(
    const float* __restrict__ hidden, const float* __restrict__ Wq,
    const float* __restrict__ Wk, const float* __restrict__ Wv,
    const float* __restrict__ dist,
    short* __restrict__ Xs, short* __restrict__ Wt, short* __restrict__ Db)
{
    __shared__ short Tl[32 * 72];
    const int bid = blockIdx.x, tid = threadIdx.x;

    if (bid < 2048) {                      // X: 128 m-tiles x 16 k-groups
        const int mt = bid >> 4, kg = bid & 15;
        const int m_l = tid >> 3, k8 = (tid & 7) * 8;
        const float* src = hidden + (size_t)(mt * 32 + m_l) * 1024 + kg * 64 + k8;
        float4 v0 = *(const float4*)src, v1 = *(const float4*)(src + 4);
        short o[8];
        o[0] = f2bf(v0.x); o[1] = f2bf(v0.y); o[2] = f2bf(v0.z); o[3] = f2bf(v0.w);
        o[4] = f2bf(v1.x); o[5] = f2bf(v1.y); o[6] = f2bf(v1.z); o[7] = f2bf(v1.w);
        *(bfrag*)&Tl[m_l * 72 + k8] = *(bfrag*)o;
        __syncthreads();
        const int l31 = tid & 31, q2 = (tid >> 5) & 1, kc = tid >> 6;
        bfrag r = *(const bfrag*)&Tl[l31 * 72 + kc * 16 + q2 * 8];
        *(bfrag*)(Xs + ((size_t)(mt * 64 + kg * 4 + kc) * 64 + q2 * 32 + l31) * 8) = r;
    } else if (bid < 3584) {               // W: 3 z x 32 n-tiles x 16 k-groups
        const int t = bid - 2048, z = t >> 9, nt = (t >> 4) & 31, kg = t & 15;
        const float* W = (z == 0) ? Wq : ((z == 1) ? Wk : Wv);
        const int k_l = tid >> 2, n8 = (tid & 3) * 8;
        const float* src = W + (size_t)(kg * 64 + k_l) * 1024 + nt * 32 + n8;
        float4 v0 = *(const float4*)src, v1 = *(const float4*)(src + 4);
        float vv[8] = {v0.x, v0.y, v0.z, v0.w, v1.x, v1.y, v1.z, v1.w};
#pragma unroll
        for (int i = 0; i < 8; i++)
            Tl[(n8 + i) * 72 + k_l] = f2bf(vv[i]);   // transpose into LDS
        __syncthreads();
        const int l31 = tid & 31, q2 = (tid >> 5) & 1, kc = tid >> 6;
        bfrag r = *(const bfrag*)&Tl[l31 * 72 + kc * 16 + q2 * 8];
        *(bfrag*)(Wt + (size_t)z * 1048576
                  + ((size_t)(nt * 64 + kg * 4 + kc) * 64 + q2 * 32 + l31) * 8) = r;
    } else {                               // dist: 2047*64 = 131008 elems
        const int idx = (bid - 3584) * 256 + tid;
        if (idx < 16376) {
            const float* src = dist + (size_t)idx * 8;
            float4 v0 = *(const float4*)src, v1 = *(const float4*)(src + 4);
            short o[8];
            o[0] = f2bf(v0.x); o[1] = f2bf(v0.y); o[2] = f2bf(v0.z); o[3] = f2bf(v0.w);
            o[4] = f2bf(v1.x); o[5] = f2bf(v1.y); o[6] = f2bf(v1.z); o[7] = f2bf(v1.w);
            *(bfrag*)(Db + (size_t)idx * 8) = *(bfrag*)o;
        }
    }
}

// ---------------------------------------------------------------------------
// QKV GEMM, LDS-free. 128x128 block, 4 waves 2x2 of 64x64.
// K-loop prefetch depth 4 (16 outstanding dwordx4; static rotation kc&3).
__global__ __launch_bounds__(256) void qkv_mfma(
    const short* __restrict__ Xs, const short* __restrict__ Wt,
    const float* __restrict__ bq, const float* __restrict__ bk,
    const float* __restrict__ bv,
    short* __restrict__ Qf, short* __restrict__ Kf, short* __restrict__ Vt)
{
    const int z = blockIdx.z;
    const short* W = Wt + (size_t)z * 1048576;
    const float* bias = (z == 0) ? bq : ((z == 1) ? bk : bv);
    // fold 1/sqrt(D) AND log2(e) into Q: 0.125 * 1.4426950408889634
    const float scale = (z == 0) ? 0.18033688011112042f : 1.0f;

    const int tid = threadIdx.x, lane = tid & 63, wid = tid >> 6;
    const int q2 = lane >> 5, l31 = lane & 31;
    const int wr = wid >> 1, wc = wid & 1;
    const int m0 = blockIdx.x * 128, n0 = blockIdx.y * 128;

    cfrag acc[2][2];
#pragma unroll
    for (int i = 0; i < 2; i++)
#pragma unroll
        for (int j = 0; j < 2; j++)
#pragma unroll
            for (int e = 0; e < 16; e++) acc[i][j][e] = 0.f;

    const short* ap0 = Xs + ((size_t)((m0 >> 5) + wr * 2 + 0) * 64 * 64 + lane) * 8;
    const short* ap1 = Xs + ((size_t)((m0 >> 5) + wr * 2 + 1) * 64 * 64 + lane) * 8;
    const short* bp0 = W  + ((size_t)((n0 >> 5) + wc * 2 + 0) * 64 * 64 + lane) * 8;
    const short* bp1 = W  + ((size_t)((n0 >> 5) + wc * 2 + 1) * 64 * 64 + lane) * 8;

    bfrag A0[4], A1[4], B0[4], B1[4];
#pragma unroll
    for (int g = 0; g < 4; g++) {          // prologue: 16 loads in flight
        const int off = g * 512;
        A0[g] = *(const bfrag*)(ap0 + off); A1[g] = *(const bfrag*)(ap1 + off);
        B0[g] = *(const bfrag*)(bp0 + off); B1[g] = *(const bfrag*)(bp1 + off);
    }

#pragma unroll 4
    for (int kc = 0; kc < 64; kc++) {
        const int s = kc & 3;              // static after unroll-4
        acc[0][0] = __builtin_amdgcn_mfma_f32_32x32x16_bf16(A0[s], B0[s], acc[0][0], 0, 0, 0);
        acc[0][1] = __builtin_amdgcn_mfma_f32_32x32x16_bf16(A0[s], B1[s], acc[0][1], 0, 0, 0);
        acc[1][0] = __builtin_amdgcn_mfma_f32_32x32x16_bf16(A1[s], B0[s], acc[1][0], 0, 0, 0);
        acc[1][1] = __builtin_amdgcn_mfma_f32_32x32x16_bf16(A1[s], B1[s], acc[1][1], 0, 0, 0);
        if (kc + 4 < 64) {                 // refill slot s for group kc+4
            const int off = (kc + 4) * 512;
            A0[s] = *(const bfrag*)(ap0 + off); A1[s] = *(const bfrag*)(ap1 + off);
            B0[s] = *(const bfrag*)(bp0 + off); B1[s] = *(const bfrag*)(bp1 + off);
        }
    }

    // epilogue: +bias, (Q: x scale), cvt bf16, scatter frag-major per bh
#pragma unroll
    for (int nt = 0; nt < 2; nt++) {
        const int c = n0 + wc * 64 + nt * 32 + l31;    // channel
        const float bval = bias[c];
        const int h = c >> 6;
        const int d = nt * 32 + l31;                   // c & 63
#pragma unroll
        for (int mt = 0; mt < 2; mt++) {
            const int tok0 = m0 + wr * 64 + mt * 32;
            const int bb = tok0 >> 10, s_base = tok0 & 1023;
            const size_t bhbase = (size_t)(bb * 16 + h) * 65536;
            if (z < 2) {
                short* outp = (z == 0) ? Qf : Kf;
                const size_t fbase = bhbase
                    + ((size_t)((s_base >> 5) * 4 + (d >> 4)) * 64
                       + ((d >> 3) & 1) * 32) * 8 + (d & 7);
#pragma unroll
                for (int reg = 0; reg < 16; reg++) {
                    const int row = (reg & 3) + 8 * (reg >> 2) + 4 * q2;
                    outp[fbase + (size_t)row * 8] = f2bf((acc[mt][nt][reg] + bval) * scale);
                }
            } else {
                // V^T frag-major: elem (d, s): ((d>>5)*64 + (s>>4))*64*8 ...
#pragma unroll
                for (int g = 0; g < 4; g++) {
                    const float e0 = acc[mt][nt][4 * g + 0] + bval;
                    const float e1 = acc[mt][nt][4 * g + 1] + bval;
                    const float e2 = acc[mt][nt][4 * g + 2] + bval;
                    const float e3 = acc[mt][nt][4 * g + 3] + bval;
                    uint2 w2;
                    w2.x = pk2(f2bf(e0), f2bf(e1));
                    w2.y = pk2(f2bf(e2), f2bf(e3));
                    const size_t flat = bhbase
                        + ((size_t)(nt * 64 + (s_base >> 4) + (g >> 1)) * 64
                           + (g & 1) * 32 + l31) * 8 + 4 * q2;
                    *(uint2*)(Vt + flat) = w2;
                }
            }
        }
    }
}

// ---------------------------------------------------------------------------
// Fused attention — R14 verbatim (62.2us verified, VGPR 100, no spill).
// grid (64 bh, 8 l-tiles), 256 thr (4 waves). Wave w owns l-cols
// [l0+32w, +32) for all r. Barrier-free main loop. Toeplitz ring indexed
// BY R: row l31 holds T(lg - r) at slot r&127; production pipelined one
// iteration ahead; T enters scores as the MFMA C-operand.
__global__ __launch_bounds__(256, 2) void attn_mfma(
    const short* __restrict__ Qf, const short* __restrict__ Kf,
    const short* __restrict__ Vt, const short* __restrict__ Db,
    const float* __restrict__ amask, const int* __restrict__ skim,
    float* __restrict__ out)
{
    __shared__ short Tb[128 * 132];   // per-(wave,lane) r-ring, stride 132
    __shared__ float Lg[1024];        // g[r] = exp(amask)*skim

    const int tid = threadIdx.x, lane = tid & 63, w = tid >> 6;
    const int q2 = lane >> 5, l31 = lane & 31;
    const int bh = blockIdx.x, b = bh >> 4, hh = bh & 15;
    const int l0 = blockIdx.y * 128;

    {
        const int r4 = tid * 4;
        float4 am = *(const float4*)(amask + b * 1024 + r4);
        int4 sk = *(const int4*)(skim + b * 1024 + r4);
        Lg[r4 + 0] = __expf(am.x) * (float)sk.x;
        Lg[r4 + 1] = __expf(am.y) * (float)sk.y;
        Lg[r4 + 2] = __expf(am.z) * (float)sk.z;
        Lg[r4 + 3] = __expf(am.w) * (float)sk.w;
    }
    __syncthreads();

    const short* Qg = Qf + (size_t)bh * 65536;
    const short* Kg = Kf + (size_t)bh * 65536;
    const short* Vg = Vt + (size_t)bh * 65536;

    // Q B-frags (pre-scaled by log2e/8)
    bfrag qa[4];
#pragma unroll
    for (int c = 0; c < 4; c++)
        qa[c] = *(const bfrag*)(Qg + ((size_t)(((l0 >> 5) + w) * 4 + c) * 64 + lane) * 8);

    cfrag oacc[2];
#pragma unroll
    for (int mt = 0; mt < 2; mt++)
#pragma unroll
        for (int e = 0; e < 16; e++) oacc[mt][e] = 0.f;
    v2f es01 = {0.f, 0.f}, es23 = {0.f, 0.f};

    const int Lband = l0 + 32 * w;          // wave's first l-column
    const int lg = Lband + l31;             // this lane's l-column
    const int rowb = (32 * w + l31) * 132;  // private ring row (shorts)

    for (int r0 = -128; r0 < 1024; r0 += 64) {
        const bool produce = r0 < 960;

        // ---- issue production's Db loads early (independent) ----
        bfrag pb[2][4];
        if (produce) {
#pragma unroll
            for (int mt = 0; mt < 2; mt++) {
                const int D0 = Lband - r0 - 128 + 32 * mt;   // dist block base
                const int er = min(max(D0 + l31 + 1023, 0), 2046);
#pragma unroll
                for (int kc = 0; kc < 4; kc++)
                    pb[mt][kc] = *(const bfrag*)(Db + (size_t)er * 64 + kc * 16 + q2 * 8);
            }
        }

        if (r0 >= 0) {
            // ---- K, V frag loads and ring reads, all hoisted ----
            bfrag kb[2][4], vbl[4][2];
            v2i trr[2][4];
#pragma unroll
            for (int mt = 0; mt < 2; mt++)
#pragma unroll
                for (int kc = 0; kc < 4; kc++)
                    kb[mt][kc] = *(const bfrag*)(Kg
                        + ((size_t)(((r0 >> 5) + mt) * 4 + kc) * 64 + lane) * 8);
#pragma unroll
            for (int kc = 0; kc < 4; kc++)
#pragma unroll
                for (int mtd = 0; mtd < 2; mtd++)
                    vbl[kc][mtd] = *(const bfrag*)(Vg
                        + ((size_t)(mtd * 64 + (r0 >> 4) + kc) * 64 + lane) * 8);
#pragma unroll
            for (int mt = 0; mt < 2; mt++)
#pragma unroll
                for (int g = 0; g < 4; g++)
                    trr[mt][g] = *(const v2i*)&Tb[rowb
                        + ((r0 + 32 * mt + 8 * g + 4 * q2) & 127)];

            // ---- per 32-r block: scores (C=T), softmax, relayout, PV ----
#pragma unroll
            for (int mt = 0; mt < 2; mt++) {
                cfrag sfr;
#pragma unroll
                for (int g = 0; g < 4; g++) {
                    const v2i t2 = trr[mt][g];
                    sfr[4 * g + 0] = __builtin_bit_cast(float, (unsigned)t2[0] << 16);
                    sfr[4 * g + 1] = __builtin_bit_cast(float, (unsigned)t2[0] & 0xffff0000u);
                    sfr[4 * g + 2] = __builtin_bit_cast(float, (unsigned)t2[1] << 16);
                    sfr[4 * g + 3] = __builtin_bit_cast(float, (unsigned)t2[1] & 0xffff0000u);
                }
                __builtin_amdgcn_s_setprio(1);
#pragma unroll
                for (int kc = 0; kc < 4; kc++)
                    sfr = __builtin_amdgcn_mfma_f32_32x32x16_bf16(
                        kb[mt][kc], qa[kc], sfr, 0, 0, 0);
                __builtin_amdgcn_s_setprio(0);

                unsigned int P[4][2];
#pragma unroll
                for (int g = 0; g < 4; g++) {
                    const int rb = r0 + 32 * mt + 8 * g + 4 * q2;
                    float4 g4 = *(const float4*)&Lg[rb];
                    float ev0 = __builtin_amdgcn_exp2f(sfr[4 * g + 0]) * g4.x;
                    float ev1 = __builtin_amdgcn_exp2f(sfr[4 * g + 1]) * g4.y;
                    float ev2 = __builtin_amdgcn_exp2f(sfr[4 * g + 2]) * g4.z;
                    float ev3 = __builtin_amdgcn_exp2f(sfr[4 * g + 3]) * g4.w;
                    es01 += (v2f){ev0, ev1};
                    es23 += (v2f){ev2, ev3};
                    P[g][0] = pk2(f2bf(ev0), f2bf(ev1));
                    P[g][1] = pk2(f2bf(ev2), f2bf(ev3));
                }
                // in-register relayout: score C-frag -> PV B-frag
#pragma unroll
                for (int c = 0; c < 2; c++) {
                    v2i s0 = __builtin_amdgcn_permlane32_swap(
                        (int)P[2 * c][0], (int)P[2 * c + 1][0], false, false);
                    v2i s1 = __builtin_amdgcn_permlane32_swap(
                        (int)P[2 * c][1], (int)P[2 * c + 1][1], false, false);
                    union { bfrag f; int d[4]; } u;
                    u.d[0] = s0[0]; u.d[1] = s1[0]; u.d[2] = s0[1]; u.d[3] = s1[1];
                    const int kc = 2 * mt + c;
                    __builtin_amdgcn_s_setprio(1);
#pragma unroll
                    for (int mtd = 0; mtd < 2; mtd++)
                        oacc[mtd] = __builtin_amdgcn_mfma_f32_32x32x16_bf16(
                            vbl[kc][mtd], u.f, oacc[mtd], 0, 0, 0);
                    __builtin_amdgcn_s_setprio(0);
                }
            }
        }

        // ---- production: T window for [r0+64, r0+127] (after gathers) ----
        if (produce) {
#pragma unroll
            for (int mt = 0; mt < 2; mt++) {
                cfrag t;
#pragma unroll
                for (int e = 0; e < 16; e++) t[e] = 0.f;
                __builtin_amdgcn_s_setprio(1);
#pragma unroll
                for (int kc = 0; kc < 4; kc++)
                    t = __builtin_amdgcn_mfma_f32_32x32x16_bf16(
                        pb[mt][kc], qa[kc], t, 0, 0, 0);
                __builtin_amdgcn_s_setprio(0);
#pragma unroll
                for (int e = 0; e < 16; e++) {
                    const int rr = (e & 3) + 8 * (e >> 2) + 4 * q2;
                    Tb[rowb + ((l31 + r0 - 32 * mt - rr) & 127)] = f2bf(t[e]);
                }
            }
        }
    }

    // ---- finalize ----
    float esum = (es01[0] + es01[1]) + (es23[0] + es23[1]);
    const float den = EPSV + esum + __shfl_xor(esum, 32);
    const float inv = 1.0f / den;
    float* ob = out + ((size_t)(b * 1024 + lg) * 1024) + hh * 64;
#pragma unroll
    for (int mtd = 0; mtd < 2; mtd++) {
#pragma unroll
        for (int g = 0; g < 4; g++) {
            float4 o;
            o.x = oacc[mtd][4 * g + 0] * inv;
            o.y = oacc[mtd][4 * g + 1] * inv;
            o.z = oacc[mtd][4 * g + 2] * inv;
            o.w = oacc[mtd][4 * g + 3] * inv;
            *(float4*)(ob + 32 * mtd + 8 * g + 4 * q2) = o;
        }
    }
}

// ---------------------------------------------------------------------------
extern "C" void kernel_launch(void* const* d_in, const int* in_sizes, int n_in,
                              void* d_out, int out_size, void* d_ws, size_t ws_size,
                              hipStream_t stream) {
    const float* hidden = (const float*)d_in[0];
    const float* amask  = (const float*)d_in[1];
    const int*   skim   = (const int*)d_in[2];
    const float* Wq     = (const float*)d_in[3];
    const float* bq     = (const float*)d_in[4];
    const float* Wk     = (const float*)d_in[5];
    const float* bk     = (const float*)d_in[6];
    const float* Wv     = (const float*)d_in[7];
    const float* bv     = (const float*)d_in[8];
    const float* dist   = (const float*)d_in[9];
    float* out = (float*)d_out;

    char* w = (char*)d_ws;
    short* Xs  = (short*)(w);                        // 8 MB frag-major X
    short* Wt  = (short*)(w + ((size_t)8 << 20));    // 6 MB frag-major W^T
    short* Db  = (short*)(w + ((size_t)14 << 20));   // 0.25 MB dist bf16
    short* Qf  = (short*)(w + ((size_t)15 << 20));   // 8 MB frag-major Q
    short* Kf  = (short*)(w + ((size_t)23 << 20));   // 8 MB frag-major K
    short* Vt  = (short*)(w + ((size_t)31 << 20));   // 8 MB frag-major V^T

    prep<<<3648, 256, 0, stream>>>(hidden, Wq, Wk, Wv, dist, Xs, Wt, Db);
    qkv_mfma<<<dim3(32, 8, 3), 256, 0, stream>>>(Xs, Wt, bq, bk, bv, Qf, Kf, Vt);
    attn_mfma<<<dim3(64, 8), 256, 0, stream>>>(Qf, Kf, Vt, Db, amask, skim, out);
}

// Round 10
// 181.651 us; speedup vs baseline: 1.2874x; 1.0235x over previous
//
#include <hip/hip_runtime.h>
#include <hip/hip_bf16.h>

// BertSelfAttention B=4,S=1024,HID=1024,H=16,D=64,MAXP=1024 — Round 17.
// R16: consolidated baseline 185.9us (attn 62.6 reproducible, VGPR 100).
// attn steady state: VALUBusy 35 + MfmaUtil 17 => ~48% dual-stall; chain
// arithmetic explains ~60% of cycle budget -> rest is K/V memory stall.
// K/V frag addresses are wave-INDEPENDENT: all 4 waves load identical
// 16KB/iter from L2 (4x redundant), kb consumed ~tens of cycles after
// issue. R15 proved register dbuf can't fix it (VGPR cliff ~100).
// R17: VGPR-NEUTRAL fix — global_load_lds double-buffered K/V staging
// (T3 2-phase): stage iter i+1 into buf^1 at top of iter i (staging split
// across waves, 4x1KB chunks each), consume via ds_read_b128 from buf,
// one __syncthreads/iter (its implicit vmcnt drain = staging guarantee).
// LDS 37.9->69KB (still 2 blocks/CU). pb/trr/Tb unchanged; qkv/prep = R16.
// Spill alarm: attn WRITE_SIZE > 17MB. Dead-theory readout: attn 62.6 +-2.
// ws: Xs[0,8M) Wt[8M,14M) Db[14M,14.25M) Qf[15M) Kf[23M) Vt[31M)

#define EPSV 1e-8f

typedef short bfrag __attribute__((ext_vector_type(8)));   // 8 bf16
typedef float cfrag __attribute__((ext_vector_type(16)));  // C/D 32x32
typedef int v2i __attribute__((ext_vector_type(2)));
typedef float v2f __attribute__((ext_vector_type(2)));

__device__ __forceinline__ short f2bf(float f) {
    __hip_bfloat16 h = __float2bfloat16(f);
    return *reinterpret_cast<short*>(&h);
}
__device__ __forceinline__ unsigned int pk2(short a, short b) {
    return (unsigned int)(unsigned short)a | ((unsigned int)(unsigned short)b << 16);
}
// async global->LDS DMA, 16B/lane: LDS dst = wave-uniform base + lane*16,
// global src = per-lane address (must include lane*16).
__device__ __forceinline__ void g2lds(const short* g, short* l) {
    __builtin_amdgcn_global_load_lds(
        (const __attribute__((address_space(1))) void*)g,
        (__attribute__((address_space(3))) void*)l, 16, 0, 0);
}

// ---------------------------------------------------------------------------
// prep: fused cvt/swizzle. grid.x = 3648, 256 thr.  (R16 verbatim)
__global__ __launch_bounds__(256) void prep(
    const float* __restrict__ hidden, const float* __restrict__ Wq,
    const float* __restrict__ Wk, const float* __restrict__ Wv,
    const float* __restrict__ dist,
    short* __restrict__ Xs, short* __restrict__ Wt, short* __restrict__ Db)
{
    __shared__ short Tl[32 * 72];
    const int bid = blockIdx.x, tid = threadIdx.x;

    if (bid < 2048) {                      // X: 128 m-tiles x 16 k-groups
        const int mt = bid >> 4, kg = bid & 15;
        const int m_l = tid >> 3, k8 = (tid & 7) * 8;
        const float* src = hidden + (size_t)(mt * 32 + m_l) * 1024 + kg * 64 + k8;
        float4 v0 = *(const float4*)src, v1 = *(const float4*)(src + 4);
        short o[8];
        o[0] = f2bf(v0.x); o[1] = f2bf(v0.y); o[2] = f2bf(v0.z); o[3] = f2bf(v0.w);
        o[4] = f2bf(v1.x); o[5] = f2bf(v1.y); o[6] = f2bf(v1.z); o[7] = f2bf(v1.w);
        *(bfrag*)&Tl[m_l * 72 + k8] = *(bfrag*)o;
        __syncthreads();
        const int l31 = tid & 31, q2 = (tid >> 5) & 1, kc = tid >> 6;
        bfrag r = *(const bfrag*)&Tl[l31 * 72 + kc * 16 + q2 * 8];
        *(bfrag*)(Xs + ((size_t)(mt * 64 + kg * 4 + kc) * 64 + q2 * 32 + l31) * 8) = r;
    } else if (bid < 3584) {               // W: 3 z x 32 n-tiles x 16 k-groups
        const int t = bid - 2048, z = t >> 9, nt = (t >> 4) & 31, kg = t & 15;
        const float* W = (z == 0) ? Wq : ((z == 1) ? Wk : Wv);
        const int k_l = tid >> 2, n8 = (tid & 3) * 8;
        const float* src = W + (size_t)(kg * 64 + k_l) * 1024 + nt * 32 + n8;
        float4 v0 = *(const float4*)src, v1 = *(const float4*)(src + 4);
        float vv[8] = {v0.x, v0.y, v0.z, v0.w, v1.x, v1.y, v1.z, v1.w};
#pragma unroll
        for (int i = 0; i < 8; i++)
            Tl[(n8 + i) * 72 + k_l] = f2bf(vv[i]);   // transpose into LDS
        __syncthreads();
        const int l31 = tid & 31, q2 = (tid >> 5) & 1, kc = tid >> 6;
        bfrag r = *(const bfrag*)&Tl[l31 * 72 + kc * 16 + q2 * 8];
        *(bfrag*)(Wt + (size_t)z * 1048576
                  + ((size_t)(nt * 64 + kg * 4 + kc) * 64 + q2 * 32 + l31) * 8) = r;
    } else {                               // dist: 2047*64 = 131008 elems
        const int idx = (bid - 3584) * 256 + tid;
        if (idx < 16376) {
            const float* src = dist + (size_t)idx * 8;
            float4 v0 = *(const float4*)src, v1 = *(const float4*)(src + 4);
            short o[8];
            o[0] = f2bf(v0.x); o[1] = f2bf(v0.y); o[2] = f2bf(v0.z); o[3] = f2bf(v0.w);
            o[4] = f2bf(v1.x); o[5] = f2bf(v1.y); o[6] = f2bf(v1.z); o[7] = f2bf(v1.w);
            *(bfrag*)(Db + (size_t)idx * 8) = *(bfrag*)o;
        }
    }
}

// ---------------------------------------------------------------------------
// QKV GEMM, LDS-free. 128x128 block, 4 waves 2x2 of 64x64.  (R16 verbatim)
// K-loop prefetch depth 4 (16 outstanding dwordx4; static rotation kc&3).
__global__ __launch_bounds__(256) void qkv_mfma(
    const short* __restrict__ Xs, const short* __restrict__ Wt,
    const float* __restrict__ bq, const float* __restrict__ bk,
    const float* __restrict__ bv,
    short* __restrict__ Qf, short* __restrict__ Kf, short* __restrict__ Vt)
{
    const int z = blockIdx.z;
    const short* W = Wt + (size_t)z * 1048576;
    const float* bias = (z == 0) ? bq : ((z == 1) ? bk : bv);
    // fold 1/sqrt(D) AND log2(e) into Q: 0.125 * 1.4426950408889634
    const float scale = (z == 0) ? 0.18033688011112042f : 1.0f;

    const int tid = threadIdx.x, lane = tid & 63, wid = tid >> 6;
    const int q2 = lane >> 5, l31 = lane & 31;
    const int wr = wid >> 1, wc = wid & 1;
    const int m0 = blockIdx.x * 128, n0 = blockIdx.y * 128;

    cfrag acc[2][2];
#pragma unroll
    for (int i = 0; i < 2; i++)
#pragma unroll
        for (int j = 0; j < 2; j++)
#pragma unroll
            for (int e = 0; e < 16; e++) acc[i][j][e] = 0.f;

    const short* ap0 = Xs + ((size_t)((m0 >> 5) + wr * 2 + 0) * 64 * 64 + lane) * 8;
    const short* ap1 = Xs + ((size_t)((m0 >> 5) + wr * 2 + 1) * 64 * 64 + lane) * 8;
    const short* bp0 = W  + ((size_t)((n0 >> 5) + wc * 2 + 0) * 64 * 64 + lane) * 8;
    const short* bp1 = W  + ((size_t)((n0 >> 5) + wc * 2 + 1) * 64 * 64 + lane) * 8;

    bfrag A0[4], A1[4], B0[4], B1[4];
#pragma unroll
    for (int g = 0; g < 4; g++) {          // prologue: 16 loads in flight
        const int off = g * 512;
        A0[g] = *(const bfrag*)(ap0 + off); A1[g] = *(const bfrag*)(ap1 + off);
        B0[g] = *(const bfrag*)(bp0 + off); B1[g] = *(const bfrag*)(bp1 + off);
    }

#pragma unroll 4
    for (int kc = 0; kc < 64; kc++) {
        const int s = kc & 3;              // static after unroll-4
        acc[0][0] = __builtin_amdgcn_mfma_f32_32x32x16_bf16(A0[s], B0[s], acc[0][0], 0, 0, 0);
        acc[0][1] = __builtin_amdgcn_mfma_f32_32x32x16_bf16(A0[s], B1[s], acc[0][1], 0, 0, 0);
        acc[1][0] = __builtin_amdgcn_mfma_f32_32x32x16_bf16(A1[s], B0[s], acc[1][0], 0, 0, 0);
        acc[1][1] = __builtin_amdgcn_mfma_f32_32x32x16_bf16(A1[s], B1[s], acc[1][1], 0, 0, 0);
        if (kc + 4 < 64) {                 // refill slot s for group kc+4
            const int off = (kc + 4) * 512;
            A0[s] = *(const bfrag*)(ap0 + off); A1[s] = *(const bfrag*)(ap1 + off);
            B0[s] = *(const bfrag*)(bp0 + off); B1[s] = *(const bfrag*)(bp1 + off);
        }
    }

    // epilogue: +bias, (Q: x scale), cvt bf16, scatter frag-major per bh
#pragma unroll
    for (int nt = 0; nt < 2; nt++) {
        const int c = n0 + wc * 64 + nt * 32 + l31;    // channel
        const float bval = bias[c];
        const int h = c >> 6;
        const int d = nt * 32 + l31;                   // c & 63
#pragma unroll
        for (int mt = 0; mt < 2; mt++) {
            const int tok0 = m0 + wr * 64 + mt * 32;
            const int bb = tok0 >> 10, s_base = tok0 & 1023;
            const size_t bhbase = (size_t)(bb * 16 + h) * 65536;
            if (z < 2) {
                short* outp = (z == 0) ? Qf : Kf;
                const size_t fbase = bhbase
                    + ((size_t)((s_base >> 5) * 4 + (d >> 4)) * 64
                       + ((d >> 3) & 1) * 32) * 8 + (d & 7);
#pragma unroll
                for (int reg = 0; reg < 16; reg++) {
                    const int row = (reg & 3) + 8 * (reg >> 2) + 4 * q2;
                    outp[fbase + (size_t)row * 8] = f2bf((acc[mt][nt][reg] + bval) * scale);
                }
            } else {
                // V^T frag-major: elem (d, s): ((d>>5)*64 + (s>>4))*64*8 ...
#pragma unroll
                for (int g = 0; g < 4; g++) {
                    const float e0 = acc[mt][nt][4 * g + 0] + bval;
                    const float e1 = acc[mt][nt][4 * g + 1] + bval;
                    const float e2 = acc[mt][nt][4 * g + 2] + bval;
                    const float e3 = acc[mt][nt][4 * g + 3] + bval;
                    uint2 w2;
                    w2.x = pk2(f2bf(e0), f2bf(e1));
                    w2.y = pk2(f2bf(e2), f2bf(e3));
                    const size_t flat = bhbase
                        + ((size_t)(nt * 64 + (s_base >> 4) + (g >> 1)) * 64
                           + (g & 1) * 32 + l31) * 8 + 4 * q2;
                    *(uint2*)(Vt + flat) = w2;
                }
            }
        }
    }
}

// ---------------------------------------------------------------------------
// Fused attention. grid (64 bh, 8 l-tiles), 256 thr (4 waves).
// Wave w owns l-cols [l0+32w, +32) for all r. Toeplitz ring indexed BY R
// (row l31, slot r&127), production one iter ahead, T as MFMA C-operand.
// NEW (R17): K/V staged into LDS double-buffer via global_load_lds one
// iteration ahead (staging split across waves, 4x1KB chunks each); frags
// consumed via ds_read_b128; one __syncthreads/iter (its implicit vmcnt
// drain completes the staging).
__global__ __launch_bounds__(256, 2) void attn_mfma(
    const short* __restrict__ Qf, const short* __restrict__ Kf,
    const short* __restrict__ Vt, const short* __restrict__ Db,
    const float* __restrict__ amask, const int* __restrict__ skim,
    float* __restrict__ out)
{
    __shared__ alignas(16) short Tb[128 * 132];   // per-(wave,lane) r-ring
    __shared__ alignas(16) short Kbuf[2][4096];   // 8KB per buf: K chunks
    __shared__ alignas(16) short Vbuf[2][4096];   // 8KB per buf: V chunks
    __shared__ float Lg[1024];                    // g[r] = exp(amask)*skim

    const int tid = threadIdx.x, lane = tid & 63, w = tid >> 6;
    const int q2 = lane >> 5, l31 = lane & 31;
    const int bh = blockIdx.x, b = bh >> 4, hh = bh & 15;
    const int l0 = blockIdx.y * 128;

    const short* Qg = Qf + (size_t)bh * 65536;
    const short* Kg = Kf + (size_t)bh * 65536;
    const short* Vg = Vt + (size_t)bh * 65536;

    // stage K/V for r-block rk into buf bi. 16 chunks of 1KB; wave w takes
    // chunks 4w..4w+3. c<8: K chunk (rk>>5)*4+c; c in [8,12): V mtd0 chunk
    // (rk>>4)+(c-8); c in [12,16): V mtd1 chunk 64+(rk>>4)+(c-12).
    auto STAGE = [&](int rk, int bi) {
        const int kbase = (rk >> 5) * 4, vbase = rk >> 4;
#pragma unroll
        for (int j = 0; j < 4; j++) {
            const int c = 4 * w + j;
            if (c < 8) {
                g2lds(Kg + (size_t)(kbase + c) * 512 + lane * 8,
                      &Kbuf[bi][c * 512]);
            } else if (c < 12) {
                g2lds(Vg + (size_t)(vbase + (c - 8)) * 512 + lane * 8,
                      &Vbuf[bi][(c - 8) * 512]);
            } else {
                g2lds(Vg + (size_t)(64 + vbase + (c - 12)) * 512 + lane * 8,
                      &Vbuf[bi][(c - 12 + 4) * 512]);
            }
        }
    };

    {
        const int r4 = tid * 4;
        float4 am = *(const float4*)(amask + b * 1024 + r4);
        int4 sk = *(const int4*)(skim + b * 1024 + r4);
        Lg[r4 + 0] = __expf(am.x) * (float)sk.x;
        Lg[r4 + 1] = __expf(am.y) * (float)sk.y;
        Lg[r4 + 2] = __expf(am.z) * (float)sk.z;
        Lg[r4 + 3] = __expf(am.w) * (float)sk.w;
    }
    __syncthreads();

    // Q B-frags (pre-scaled by log2e/8)
    bfrag qa[4];
#pragma unroll
    for (int c = 0; c < 4; c++)
        qa[c] = *(const bfrag*)(Qg + ((size_t)(((l0 >> 5) + w) * 4 + c) * 64 + lane) * 8);

    cfrag oacc[2];
#pragma unroll
    for (int mt = 0; mt < 2; mt++)
#pragma unroll
        for (int e = 0; e < 16; e++) oacc[mt][e] = 0.f;
    v2f es01 = {0.f, 0.f}, es23 = {0.f, 0.f};

    const int Lband = l0 + 32 * w;          // wave's first l-column
    const int lg = Lband + l31;             // this lane's l-column
    const int rowb = (32 * w + l31) * 132;  // private ring row (shorts)

    for (int r0 = -128; r0 < 1024; r0 += 64) {
        const bool produce = r0 < 960;
        const int cur = (r0 >> 6) & 1;      // consume buffer (valid r0>=0)

        // ---- stage next iteration's K/V (async DMA, full-iter cover) ----
        if (r0 + 64 >= 0 && r0 + 64 < 1024)
            STAGE(r0 + 64, ((r0 + 64) >> 6) & 1);

        // ---- issue production's Db loads early (independent) ----
        bfrag pb[2][4];
        if (produce) {
#pragma unroll
            for (int mt = 0; mt < 2; mt++) {
                const int D0 = Lband - r0 - 128 + 32 * mt;   // dist block base
                const int er = min(max(D0 + l31 + 1023, 0), 2046);
#pragma unroll
                for (int kc = 0; kc < 4; kc++)
                    pb[mt][kc] = *(const bfrag*)(Db + (size_t)er * 64 + kc * 16 + q2 * 8);
            }
        }

        if (r0 >= 0) {
            // ---- K, V frags from staged LDS; ring reads; all hoisted ----
            bfrag kb[2][4], vbl[4][2];
            v2i trr[2][4];
#pragma unroll
            for (int mt = 0; mt < 2; mt++)
#pragma unroll
                for (int kc = 0; kc < 4; kc++)
                    kb[mt][kc] = *(const bfrag*)&Kbuf[cur][(mt * 4 + kc) * 512 + lane * 8];
#pragma unroll
            for (int kc = 0; kc < 4; kc++)
#pragma unroll
                for (int mtd = 0; mtd < 2; mtd++)
                    vbl[kc][mtd] = *(const bfrag*)&Vbuf[cur][(mtd * 4 + kc) * 512 + lane * 8];
#pragma unroll
            for (int mt = 0; mt < 2; mt++)
#pragma unroll
                for (int g = 0; g < 4; g++)
                    trr[mt][g] = *(const v2i*)&Tb[rowb
                        + ((r0 + 32 * mt + 8 * g + 4 * q2) & 127)];

            // ---- per 32-r block: scores (C=T), softmax, relayout, PV ----
#pragma unroll
            for (int mt = 0; mt < 2; mt++) {
                cfrag sfr;
#pragma unroll
                for (int g = 0; g < 4; g++) {
                    const v2i t2 = trr[mt][g];
                    sfr[4 * g + 0] = __builtin_bit_cast(float, (unsigned)t2[0] << 16);
                    sfr[4 * g + 1] = __builtin_bit_cast(float, (unsigned)t2[0] & 0xffff0000u);
                    sfr[4 * g + 2] = __builtin_bit_cast(float, (unsigned)t2[1] << 16);
                    sfr[4 * g + 3] = __builtin_bit_cast(float, (unsigned)t2[1] & 0xffff0000u);
                }
                __builtin_amdgcn_s_setprio(1);
#pragma unroll
                for (int kc = 0; kc < 4; kc++)
                    sfr = __builtin_amdgcn_mfma_f32_32x32x16_bf16(
                        kb[mt][kc], qa[kc], sfr, 0, 0, 0);
                __builtin_amdgcn_s_setprio(0);

                unsigned int P[4][2];
#pragma unroll
                for (int g = 0; g < 4; g++) {
                    const int rb = r0 + 32 * mt + 8 * g + 4 * q2;
                    float4 g4 = *(const float4*)&Lg[rb];
                    float ev0 = __builtin_amdgcn_exp2f(sfr[4 * g + 0]) * g4.x;
                    float ev1 = __builtin_amdgcn_exp2f(sfr[4 * g + 1]) * g4.y;
                    float ev2 = __builtin_amdgcn_exp2f(sfr[4 * g + 2]) * g4.z;
                    float ev3 = __builtin_amdgcn_exp2f(sfr[4 * g + 3]) * g4.w;
                    es01 += (v2f){ev0, ev1};
                    es23 += (v2f){ev2, ev3};
                    P[g][0] = pk2(f2bf(ev0), f2bf(ev1));
                    P[g][1] = pk2(f2bf(ev2), f2bf(ev3));
                }
                // in-register relayout: score C-frag -> PV B-frag
#pragma unroll
                for (int c = 0; c < 2; c++) {
                    v2i s0 = __builtin_amdgcn_permlane32_swap(
                        (int)P[2 * c][0], (int)P[2 * c + 1][0], false, false);
                    v2i s1 = __builtin_amdgcn_permlane32_swap(
                        (int)P[2 * c][1], (int)P[2 * c + 1][1], false, false);
                    union { bfrag f; int d[4]; } u;
                    u.d[0] = s0[0]; u.d[1] = s1[0]; u.d[2] = s0[1]; u.d[3] = s1[1];
                    const int kc = 2 * mt + c;
                    __builtin_amdgcn_s_setprio(1);
#pragma unroll
                    for (int mtd = 0; mtd < 2; mtd++)
                        oacc[mtd] = __builtin_amdgcn_mfma_f32_32x32x16_bf16(
                            vbl[kc][mtd], u.f, oacc[mtd], 0, 0, 0);
                    __builtin_amdgcn_s_setprio(0);
                }
            }
        }

        // ---- production: T window for [r0+64, r0+127] (after gathers) ----
        if (produce) {
#pragma unroll
            for (int mt = 0; mt < 2; mt++) {
                cfrag t;
#pragma unroll
                for (int e = 0; e < 16; e++) t[e] = 0.f;
                __builtin_amdgcn_s_setprio(1);
#pragma unroll
                for (int kc = 0; kc < 4; kc++)
                    t = __builtin_amdgcn_mfma_f32_32x32x16_bf16(
                        pb[mt][kc], qa[kc], t, 0, 0, 0);
                __builtin_amdgcn_s_setprio(0);
#pragma unroll
                for (int e = 0; e < 16; e++) {
                    const int rr = (e & 3) + 8 * (e >> 2) + 4 * q2;
                    Tb[rowb + ((l31 + r0 - 32 * mt - rr) & 127)] = f2bf(t[e]);
                }
            }
        }

        // barrier: (a) completes next iter's staged DMA (implicit vmcnt
        // drain), (b) orders buf reuse across waves. Tb is wave-private.
        __syncthreads();
    }

    // ---- finalize ----
    float esum = (es01[0] + es01[1]) + (es23[0] + es23[1]);
    const float den = EPSV + esum + __shfl_xor(esum, 32);
    const float inv = 1.0f / den;
    float* ob = out + ((size_t)(b * 1024 + lg) * 1024) + hh * 64;
#pragma unroll
    for (int mtd = 0; mtd < 2; mtd++) {
#pragma unroll
        for (int g = 0; g < 4; g++) {
            float4 o;
            o.x = oacc[mtd][4 * g + 0] * inv;
            o.y = oacc[mtd][4 * g + 1] * inv;
            o.z = oacc[mtd][4 * g + 2] * inv;
            o.w = oacc[mtd][4 * g + 3] * inv;
            *(float4*)(ob + 32 * mtd + 8 * g + 4 * q2) = o;
        }
    }
}

// ---------------------------------------------------------------------------
extern "C" void kernel_launch(void* const* d_in, const int* in_sizes, int n_in,
                              void* d_out, int out_size, void* d_ws, size_t ws_size,
                              hipStream_t stream) {
    const float* hidden = (const float*)d_in[0];
    const float* amask  = (const float*)d_in[1];
    const int*   skim   = (const int*)d_in[2];
    const float* Wq     = (const float*)d_in[3];
    const float* bq     = (const float*)d_in[4];
    const float* Wk     = (const float*)d_in[5];
    const float* bk     = (const float*)d_in[6];
    const float* Wv     = (const float*)d_in[7];
    const float* bv     = (const float*)d_in[8];
    const float* dist   = (const float*)d_in[9];
    float* out = (float*)d_out;

    char* w = (char*)d_ws;
    short* Xs  = (short*)(w);                        // 8 MB frag-major X
    short* Wt  = (short*)(w + ((size_t)8 << 20));    // 6 MB frag-major W^T
    short* Db  = (short*)(w + ((size_t)14 << 20));   // 0.25 MB dist bf16
    short* Qf  = (short*)(w + ((size_t)15 << 20));   // 8 MB frag-major Q
    short* Kf  = (short*)(w + ((size_t)23 << 20));   // 8 MB frag-major K
    short* Vt  = (short*)(w + ((size_t)31 << 20));   // 8 MB frag-major V^T

    prep<<<3648, 256, 0, stream>>>(hidden, Wq, Wk, Wv, dist, Xs, Wt, Db);
    qkv_mfma<<<dim3(32, 8, 3), 256, 0, stream>>>(Xs, Wt, bq, bk, bv, Qf, Kf, Vt);
    attn_mfma<<<dim3(64, 8), 256, 0, stream>>>(Qf, Kf, Vt, Db, amask, skim, out);
}

// Round 12
// 176.301 us; speedup vs baseline: 1.3265x; 1.0303x over previous
//
#include <hip/hip_runtime.h>
#include <hip/hip_bf16.h>

// BertSelfAttention B=4,S=1024,HID=1024,H=16,D=64,MAXP=1024 — Round 19.
// R18 post-mortem: correctness fail (absmax 0.208, finite => wrong addrs).
// Bug: qkv staging base used m-tile stride 4096 SHORTS, actual layout is
// chunk (mtile,kc) at mtile*32768 + kc*512 shorts (R16's expr was
// (idx*64*64 + lane)*8 — the *8 got dropped). Staged in-bounds garbage.
// R19 = R18 with Ag/Bg/STAGE strides fixed 4096->32768. Nothing else.
// R18 theory (untested, not falsified): qkv ~90us = 290 TF, 3x below m97
// ladder; staging dedup + global_load_lds latency cover should cut it.
// Falsification: total drop <8us => qkv L3-BW-bound -> XCD swizzle next.
// ws: Xs[0,8M) Wt[8M,14M) Db[14M,14.25M) Qf[15M) Kf[23M) Vt[31M)

#define EPSV 1e-8f

typedef short bfrag __attribute__((ext_vector_type(8)));   // 8 bf16
typedef float cfrag __attribute__((ext_vector_type(16)));  // C/D 32x32
typedef int v2i __attribute__((ext_vector_type(2)));
typedef float v2f __attribute__((ext_vector_type(2)));

__device__ __forceinline__ short f2bf(float f) {
    __hip_bfloat16 h = __float2bfloat16(f);
    return *reinterpret_cast<short*>(&h);
}
__device__ __forceinline__ unsigned int pk2(short a, short b) {
    return (unsigned int)(unsigned short)a | ((unsigned int)(unsigned short)b << 16);
}
// async global->LDS DMA, 16B/lane: LDS dst = wave-uniform base + lane*16,
// global src = per-lane address (must include lane*16).
__device__ __forceinline__ void g2lds(const short* g, short* l) {
    __builtin_amdgcn_global_load_lds(
        (const __attribute__((address_space(1))) void*)g,
        (__attribute__((address_space(3))) void*)l, 16, 0, 0);
}

// ---------------------------------------------------------------------------
// prep: fused cvt/swizzle. grid.x = 3648, 256 thr.  (R16 verbatim)
__global__ __launch_bounds__(256) void prep(
    const float* __restrict__ hidden, const float* __restrict__ Wq,
    const float* __restrict__ Wk, const float* __restrict__ Wv,
    const float* __restrict__ dist,
    short* __restrict__ Xs, short* __restrict__ Wt, short* __restrict__ Db)
{
    __shared__ short Tl[32 * 72];
    const int bid = blockIdx.x, tid = threadIdx.x;

    if (bid < 2048) {                      // X: 128 m-tiles x 16 k-groups
        const int mt = bid >> 4, kg = bid & 15;
        const int m_l = tid >> 3, k8 = (tid & 7) * 8;
        const float* src = hidden + (size_t)(mt * 32 + m_l) * 1024 + kg * 64 + k8;
        float4 v0 = *(const float4*)src, v1 = *(const float4*)(src + 4);
        short o[8];
        o[0] = f2bf(v0.x); o[1] = f2bf(v0.y); o[2] = f2bf(v0.z); o[3] = f2bf(v0.w);
        o[4] = f2bf(v1.x); o[5] = f2bf(v1.y); o[6] = f2bf(v1.z); o[7] = f2bf(v1.w);
        *(bfrag*)&Tl[m_l * 72 + k8] = *(bfrag*)o;
        __syncthreads();
        const int l31 = tid & 31, q2 = (tid >> 5) & 1, kc = tid >> 6;
        bfrag r = *(const bfrag*)&Tl[l31 * 72 + kc * 16 + q2 * 8];
        *(bfrag*)(Xs + ((size_t)(mt * 64 + kg * 4 + kc) * 64 + q2 * 32 + l31) * 8) = r;
    } else if (bid < 3584) {               // W: 3 z x 32 n-tiles x 16 k-groups
        const int t = bid - 2048, z = t >> 9, nt = (t >> 4) & 31, kg = t & 15;
        const float* W = (z == 0) ? Wq : ((z == 1) ? Wk : Wv);
        const int k_l = tid >> 2, n8 = (tid & 3) * 8;
        const float* src = W + (size_t)(kg * 64 + k_l) * 1024 + nt * 32 + n8;
        float4 v0 = *(const float4*)src, v1 = *(const float4*)(src + 4);
        float vv[8] = {v0.x, v0.y, v0.z, v0.w, v1.x, v1.y, v1.z, v1.w};
#pragma unroll
        for (int i = 0; i < 8; i++)
            Tl[(n8 + i) * 72 + k_l] = f2bf(vv[i]);   // transpose into LDS
        __syncthreads();
        const int l31 = tid & 31, q2 = (tid >> 5) & 1, kc = tid >> 6;
        bfrag r = *(const bfrag*)&Tl[l31 * 72 + kc * 16 + q2 * 8];
        *(bfrag*)(Wt + (size_t)z * 1048576
                  + ((size_t)(nt * 64 + kg * 4 + kc) * 64 + q2 * 32 + l31) * 8) = r;
    } else {                               // dist: 2047*64 = 131008 elems
        const int idx = (bid - 3584) * 256 + tid;
        if (idx < 16376) {
            const float* src = dist + (size_t)idx * 8;
            float4 v0 = *(const float4*)src, v1 = *(const float4*)(src + 4);
            short o[8];
            o[0] = f2bf(v0.x); o[1] = f2bf(v0.y); o[2] = f2bf(v0.z); o[3] = f2bf(v0.w);
            o[4] = f2bf(v1.x); o[5] = f2bf(v1.y); o[6] = f2bf(v1.z); o[7] = f2bf(v1.w);
            *(bfrag*)(Db + (size_t)idx * 8) = *(bfrag*)o;
        }
    }
}

// ---------------------------------------------------------------------------
// QKV GEMM — m97-style. 128x128 block, 4 waves 2x2 of 64x64.
// BK=32 phases: 16 chunks (A[4]+B[4] x 2 k-subs, 1KB each) staged per phase
// via global_load_lds into 32KB LDS double-buffer; frags via ds_read_b128;
// 8 MFMA/phase; one __syncthreads/phase (drain = staging guarantee + buf
// reuse ordering). Chunk staged ONCE per block (dedup vs 2x before).
// Layout: chunk (tile, kc) at tile*32768 + kc*512 shorts (R19 stride fix).
__global__ __launch_bounds__(256) void qkv_mfma(
    const short* __restrict__ Xs, const short* __restrict__ Wt,
    const float* __restrict__ bq, const float* __restrict__ bk,
    const float* __restrict__ bv,
    short* __restrict__ Qf, short* __restrict__ Kf, short* __restrict__ Vt)
{
    __shared__ alignas(16) short Ab[2][2][4][512];  // [buf][ksub][chunk][1KB]
    __shared__ alignas(16) short Bb[2][2][4][512];

    const int z = blockIdx.z;
    const short* W = Wt + (size_t)z * 1048576;
    const float* bias = (z == 0) ? bq : ((z == 1) ? bk : bv);
    // fold 1/sqrt(D) AND log2(e) into Q: 0.125 * 1.4426950408889634
    const float scale = (z == 0) ? 0.18033688011112042f : 1.0f;

    const int tid = threadIdx.x, lane = tid & 63, wid = tid >> 6;
    const int q2 = lane >> 5, l31 = lane & 31;
    const int wr = wid >> 1, wc = wid & 1;
    const int m0 = blockIdx.x * 128, n0 = blockIdx.y * 128;

    // tile-0 global bases (shorts); tile t at +t*32768, chunk kc at +kc*512
    const short* Ag = Xs + (size_t)(m0 >> 5) * 32768;
    const short* Bg = W  + (size_t)(n0 >> 5) * 32768;

    // stage phase p (k-subs 2p, 2p+1) into buf bi; wave w stages chunk w of
    // A and B for both k-subs (4 g2lds per wave, 16 chunks per block).
    auto STAGE = [&](int p, int bi) {
        const int k0 = p * 2;
#pragma unroll
        for (int j = 0; j < 2; j++) {
            g2lds(Ag + (size_t)wid * 32768 + (k0 + j) * 512 + lane * 8,
                  &Ab[bi][j][wid][0]);
            g2lds(Bg + (size_t)wid * 32768 + (k0 + j) * 512 + lane * 8,
                  &Bb[bi][j][wid][0]);
        }
    };

    cfrag acc[2][2];
#pragma unroll
    for (int i = 0; i < 2; i++)
#pragma unroll
        for (int j = 0; j < 2; j++)
#pragma unroll
            for (int e = 0; e < 16; e++) acc[i][j][e] = 0.f;

    STAGE(0, 0);
    __syncthreads();                       // phase-0 staging complete

    for (int p = 0; p < 32; p++) {
        const int bi = p & 1;
        if (p + 1 < 32) STAGE(p + 1, bi ^ 1);
#pragma unroll
        for (int j = 0; j < 2; j++) {
            bfrag a0 = *(const bfrag*)&Ab[bi][j][2 * wr + 0][lane * 8];
            bfrag a1 = *(const bfrag*)&Ab[bi][j][2 * wr + 1][lane * 8];
            bfrag b0 = *(const bfrag*)&Bb[bi][j][2 * wc + 0][lane * 8];
            bfrag b1 = *(const bfrag*)&Bb[bi][j][2 * wc + 1][lane * 8];
            acc[0][0] = __builtin_amdgcn_mfma_f32_32x32x16_bf16(a0, b0, acc[0][0], 0, 0, 0);
            acc[0][1] = __builtin_amdgcn_mfma_f32_32x32x16_bf16(a0, b1, acc[0][1], 0, 0, 0);
            acc[1][0] = __builtin_amdgcn_mfma_f32_32x32x16_bf16(a1, b0, acc[1][0], 0, 0, 0);
            acc[1][1] = __builtin_amdgcn_mfma_f32_32x32x16_bf16(a1, b1, acc[1][1], 0, 0, 0);
        }
        // drain: completes phase p+1 staging; orders buf bi reuse at p+2.
        __syncthreads();
    }

    // epilogue: +bias, (Q: x scale), cvt bf16, scatter frag-major per bh
#pragma unroll
    for (int nt = 0; nt < 2; nt++) {
        const int c = n0 + wc * 64 + nt * 32 + l31;    // channel
        const float bval = bias[c];
        const int h = c >> 6;
        const int d = nt * 32 + l31;                   // c & 63
#pragma unroll
        for (int mt = 0; mt < 2; mt++) {
            const int tok0 = m0 + wr * 64 + mt * 32;
            const int bb = tok0 >> 10, s_base = tok0 & 1023;
            const size_t bhbase = (size_t)(bb * 16 + h) * 65536;
            if (z < 2) {
                short* outp = (z == 0) ? Qf : Kf;
                const size_t fbase = bhbase
                    + ((size_t)((s_base >> 5) * 4 + (d >> 4)) * 64
                       + ((d >> 3) & 1) * 32) * 8 + (d & 7);
#pragma unroll
                for (int reg = 0; reg < 16; reg++) {
                    const int row = (reg & 3) + 8 * (reg >> 2) + 4 * q2;
                    outp[fbase + (size_t)row * 8] = f2bf((acc[mt][nt][reg] + bval) * scale);
                }
            } else {
                // V^T frag-major: elem (d, s): ((d>>5)*64 + (s>>4))*64*8 ...
#pragma unroll
                for (int g = 0; g < 4; g++) {
                    const float e0 = acc[mt][nt][4 * g + 0] + bval;
                    const float e1 = acc[mt][nt][4 * g + 1] + bval;
                    const float e2 = acc[mt][nt][4 * g + 2] + bval;
                    const float e3 = acc[mt][nt][4 * g + 3] + bval;
                    uint2 w2;
                    w2.x = pk2(f2bf(e0), f2bf(e1));
                    w2.y = pk2(f2bf(e2), f2bf(e3));
                    const size_t flat = bhbase
                        + ((size_t)(nt * 64 + (s_base >> 4) + (g >> 1)) * 64
                           + (g & 1) * 32 + l31) * 8 + 4 * q2;
                    *(uint2*)(Vt + flat) = w2;
                }
            }
        }
    }
}

// ---------------------------------------------------------------------------
// Fused attention — R17 verbatim (61.5us verified). grid (64 bh, 8 l-tiles),
// 256 thr (4 waves). Toeplitz ring by r, production one iter ahead, T as
// MFMA C-operand, K/V staged via global_load_lds double-buffer.
__global__ __launch_bounds__(256, 2) void attn_mfma(
    const short* __restrict__ Qf, const short* __restrict__ Kf,
    const short* __restrict__ Vt, const short* __restrict__ Db,
    const float* __restrict__ amask, const int* __restrict__ skim,
    float* __restrict__ out)
{
    __shared__ alignas(16) short Tb[128 * 132];   // per-(wave,lane) r-ring
    __shared__ alignas(16) short Kbuf[2][4096];   // 8KB per buf: K chunks
    __shared__ alignas(16) short Vbuf[2][4096];   // 8KB per buf: V chunks
    __shared__ float Lg[1024];                    // g[r] = exp(amask)*skim

    const int tid = threadIdx.x, lane = tid & 63, w = tid >> 6;
    const int q2 = lane >> 5, l31 = lane & 31;
    const int bh = blockIdx.x, b = bh >> 4, hh = bh & 15;
    const int l0 = blockIdx.y * 128;

    const short* Qg = Qf + (size_t)bh * 65536;
    const short* Kg = Kf + (size_t)bh * 65536;
    const short* Vg = Vt + (size_t)bh * 65536;

    // stage K/V for r-block rk into buf bi. 16 chunks of 1KB; wave w takes
    // chunks 4w..4w+3. c<8: K chunk (rk>>5)*4+c; c in [8,12): V mtd0 chunk
    // (rk>>4)+(c-8); c in [12,16): V mtd1 chunk 64+(rk>>4)+(c-12).
    auto STAGE = [&](int rk, int bi) {
        const int kbase = (rk >> 5) * 4, vbase = rk >> 4;
#pragma unroll
        for (int j = 0; j < 4; j++) {
            const int c = 4 * w + j;
            if (c < 8) {
                g2lds(Kg + (size_t)(kbase + c) * 512 + lane * 8,
                      &Kbuf[bi][c * 512]);
            } else if (c < 12) {
                g2lds(Vg + (size_t)(vbase + (c - 8)) * 512 + lane * 8,
                      &Vbuf[bi][(c - 8) * 512]);
            } else {
                g2lds(Vg + (size_t)(64 + vbase + (c - 12)) * 512 + lane * 8,
                      &Vbuf[bi][(c - 12 + 4) * 512]);
            }
        }
    };

    {
        const int r4 = tid * 4;
        float4 am = *(const float4*)(amask + b * 1024 + r4);
        int4 sk = *(const int4*)(skim + b * 1024 + r4);
        Lg[r4 + 0] = __expf(am.x) * (float)sk.x;
        Lg[r4 + 1] = __expf(am.y) * (float)sk.y;
        Lg[r4 + 2] = __expf(am.z) * (float)sk.z;
        Lg[r4 + 3] = __expf(am.w) * (float)sk.w;
    }
    __syncthreads();

    // Q B-frags (pre-scaled by log2e/8)
    bfrag qa[4];
#pragma unroll
    for (int c = 0; c < 4; c++)
        qa[c] = *(const bfrag*)(Qg + ((size_t)(((l0 >> 5) + w) * 4 + c) * 64 + lane) * 8);

    cfrag oacc[2];
#pragma unroll
    for (int mt = 0; mt < 2; mt++)
#pragma unroll
        for (int e = 0; e < 16; e++) oacc[mt][e] = 0.f;
    v2f es01 = {0.f, 0.f}, es23 = {0.f, 0.f};

    const int Lband = l0 + 32 * w;          // wave's first l-column
    const int lg = Lband + l31;             // this lane's l-column
    const int rowb = (32 * w + l31) * 132;  // private ring row (shorts)

    for (int r0 = -128; r0 < 1024; r0 += 64) {
        const bool produce = r0 < 960;
        const int cur = (r0 >> 6) & 1;      // consume buffer (valid r0>=0)

        // ---- stage next iteration's K/V (async DMA, full-iter cover) ----
        if (r0 + 64 >= 0 && r0 + 64 < 1024)
            STAGE(r0 + 64, ((r0 + 64) >> 6) & 1);

        // ---- issue production's Db loads early (independent) ----
        bfrag pb[2][4];
        if (produce) {
#pragma unroll
            for (int mt = 0; mt < 2; mt++) {
                const int D0 = Lband - r0 - 128 + 32 * mt;   // dist block base
                const int er = min(max(D0 + l31 + 1023, 0), 2046);
#pragma unroll
                for (int kc = 0; kc < 4; kc++)
                    pb[mt][kc] = *(const bfrag*)(Db + (size_t)er * 64 + kc * 16 + q2 * 8);
            }
        }

        if (r0 >= 0) {
            // ---- K, V frags from staged LDS; ring reads; all hoisted ----
            bfrag kb[2][4], vbl[4][2];
            v2i trr[2][4];
#pragma unroll
            for (int mt = 0; mt < 2; mt++)
#pragma unroll
                for (int kc = 0; kc < 4; kc++)
                    kb[mt][kc] = *(const bfrag*)&Kbuf[cur][(mt * 4 + kc) * 512 + lane * 8];
#pragma unroll
            for (int kc = 0; kc < 4; kc++)
#pragma unroll
                for (int mtd = 0; mtd < 2; mtd++)
                    vbl[kc][mtd] = *(const bfrag*)&Vbuf[cur][(mtd * 4 + kc) * 512 + lane * 8];
#pragma unroll
            for (int mt = 0; mt < 2; mt++)
#pragma unroll
                for (int g = 0; g < 4; g++)
                    trr[mt][g] = *(const v2i*)&Tb[rowb
                        + ((r0 + 32 * mt + 8 * g + 4 * q2) & 127)];

            // ---- per 32-r block: scores (C=T), softmax, relayout, PV ----
#pragma unroll
            for (int mt = 0; mt < 2; mt++) {
                cfrag sfr;
#pragma unroll
                for (int g = 0; g < 4; g++) {
                    const v2i t2 = trr[mt][g];
                    sfr[4 * g + 0] = __builtin_bit_cast(float, (unsigned)t2[0] << 16);
                    sfr[4 * g + 1] = __builtin_bit_cast(float, (unsigned)t2[0] & 0xffff0000u);
                    sfr[4 * g + 2] = __builtin_bit_cast(float, (unsigned)t2[1] << 16);
                    sfr[4 * g + 3] = __builtin_bit_cast(float, (unsigned)t2[1] & 0xffff0000u);
                }
                __builtin_amdgcn_s_setprio(1);
#pragma unroll
                for (int kc = 0; kc < 4; kc++)
                    sfr = __builtin_amdgcn_mfma_f32_32x32x16_bf16(
                        kb[mt][kc], qa[kc], sfr, 0, 0, 0);
                __builtin_amdgcn_s_setprio(0);

                unsigned int P[4][2];
#pragma unroll
                for (int g = 0; g < 4; g++) {
                    const int rb = r0 + 32 * mt + 8 * g + 4 * q2;
                    float4 g4 = *(const float4*)&Lg[rb];
                    float ev0 = __builtin_amdgcn_exp2f(sfr[4 * g + 0]) * g4.x;
                    float ev1 = __builtin_amdgcn_exp2f(sfr[4 * g + 1]) * g4.y;
                    float ev2 = __builtin_amdgcn_exp2f(sfr[4 * g + 2]) * g4.z;
                    float ev3 = __builtin_amdgcn_exp2f(sfr[4 * g + 3]) * g4.w;
                    es01 += (v2f){ev0, ev1};
                    es23 += (v2f){ev2, ev3};
                    P[g][0] = pk2(f2bf(ev0), f2bf(ev1));
                    P[g][1] = pk2(f2bf(ev2), f2bf(ev3));
                }
                // in-register relayout: score C-frag -> PV B-frag
#pragma unroll
                for (int c = 0; c < 2; c++) {
                    v2i s0 = __builtin_amdgcn_permlane32_swap(
                        (int)P[2 * c][0], (int)P[2 * c + 1][0], false, false);
                    v2i s1 = __builtin_amdgcn_permlane32_swap(
                        (int)P[2 * c][1], (int)P[2 * c + 1][1], false, false);
                    union { bfrag f; int d[4]; } u;
                    u.d[0] = s0[0]; u.d[1] = s1[0]; u.d[2] = s0[1]; u.d[3] = s1[1];
                    const int kc = 2 * mt + c;
                    __builtin_amdgcn_s_setprio(1);
#pragma unroll
                    for (int mtd = 0; mtd < 2; mtd++)
                        oacc[mtd] = __builtin_amdgcn_mfma_f32_32x32x16_bf16(
                            vbl[kc][mtd], u.f, oacc[mtd], 0, 0, 0);
                    __builtin_amdgcn_s_setprio(0);
                }
            }
        }

        // ---- production: T window for [r0+64, r0+127] (after gathers) ----
        if (produce) {
#pragma unroll
            for (int mt = 0; mt < 2; mt++) {
                cfrag t;
#pragma unroll
                for (int e = 0; e < 16; e++) t[e] = 0.f;
                __builtin_amdgcn_s_setprio(1);
#pragma unroll
                for (int kc = 0; kc < 4; kc++)
                    t = __builtin_amdgcn_mfma_f32_32x32x16_bf16(
                        pb[mt][kc], qa[kc], t, 0, 0, 0);
                __builtin_amdgcn_s_setprio(0);
#pragma unroll
                for (int e = 0; e < 16; e++) {
                    const int rr = (e & 3) + 8 * (e >> 2) + 4 * q2;
                    Tb[rowb + ((l31 + r0 - 32 * mt - rr) & 127)] = f2bf(t[e]);
                }
            }
        }

        // barrier: (a) completes next iter's staged DMA (implicit vmcnt
        // drain), (b) orders buf reuse across waves. Tb is wave-private.
        __syncthreads();
    }

    // ---- finalize ----
    float esum = (es01[0] + es01[1]) + (es23[0] + es23[1]);
    const float den = EPSV + esum + __shfl_xor(esum, 32);
    const float inv = 1.0f / den;
    float* ob = out + ((size_t)(b * 1024 + lg) * 1024) + hh * 64;
#pragma unroll
    for (int mtd = 0; mtd < 2; mtd++) {
#pragma unroll
        for (int g = 0; g < 4; g++) {
            float4 o;
            o.x = oacc[mtd][4 * g + 0] * inv;
            o.y = oacc[mtd][4 * g + 1] * inv;
            o.z = oacc[mtd][4 * g + 2] * inv;
            o.w = oacc[mtd][4 * g + 3] * inv;
            *(float4*)(ob + 32 * mtd + 8 * g + 4 * q2) = o;
        }
    }
}

// ---------------------------------------------------------------------------
extern "C" void kernel_launch(void* const* d_in, const int* in_sizes, int n_in,
                              void* d_out, int out_size, void* d_ws, size_t ws_size,
                              hipStream_t stream) {
    const float* hidden = (const float*)d_in[0];
    const float* amask  = (const float*)d_in[1];
    const int*   skim   = (const int*)d_in[2];
    const float* Wq     = (const float*)d_in[3];
    const float* bq     = (const float*)d_in[4];
    const float* Wk     = (const float*)d_in[5];
    const float* bk     = (const float*)d_in[6];
    const float* Wv     = (const float*)d_in[7];
    const float* bv     = (const float*)d_in[8];
    const float* dist   = (const float*)d_in[9];
    float* out = (float*)d_out;

    char* w = (char*)d_ws;
    short* Xs  = (short*)(w);                        // 8 MB frag-major X
    short* Wt  = (short*)(w + ((size_t)8 << 20));    // 6 MB frag-major W^T
    short* Db  = (short*)(w + ((size_t)14 << 20));   // 0.25 MB dist bf16
    short* Qf  = (short*)(w + ((size_t)15 << 20));   // 8 MB frag-major Q
    short* Kf  = (short*)(w + ((size_t)23 << 20));   // 8 MB frag-major K
    short* Vt  = (short*)(w + ((size_t)31 << 20));   // 8 MB frag-major V^T

    prep<<<3648, 256, 0, stream>>>(hidden, Wq, Wk, Wv, dist, Xs, Wt, Db);
    qkv_mfma<<<dim3(32, 8, 3), 256, 0, stream>>>(Xs, Wt, bq, bk, bv, Qf, Kf, Vt);
    attn_mfma<<<dim3(64, 8), 256, 0, stream>>>(Qf, Kf, Vt, Db, amask, skim, out);
}

// Round 13
// 174.444 us; speedup vs baseline: 1.3406x; 1.0106x over previous
//
#include <hip/hip_runtime.h>
#include <hip/hip_bf16.h>

// BertSelfAttention B=4,S=1024,HID=1024,H=16,D=64,MAXP=1024 — Round 20.
// R19 post-mortem: qkv m97-rewrite gained only ~3.4us (< 8us line) — BUT
// the implementation defeated its own pipeline: __syncthreads drains
// vmcnt(0), so the per-phase prefetch is waited ~64cy after issue. Every
// phase eats a naked L2/L3 round-trip at the barrier (T4 lesson m218:
// counted-vs-drain0 = +38-73%). Traffic math rules out BW-bound (~24MB/z
// L3 with natural XCD-local A-sharing => ~5us).
// R20: qkv -> 3-buffer counted-vmcnt pipeline (m201 pattern, plain HIP):
// stage p+2 at phase p; per phase: s_waitcnt vmcnt(4) (NEVER 0 in loop) +
// raw s_barrier -> STAGE -> ds_read+MFMA. 48KB LDS (3 bufs), 3 blocks/CU.
// attn/prep frozen at R19. Readout: total flat => prep is the hidden hog.
// ws: Xs[0,8M) Wt[8M,14M) Db[14M,14.25M) Qf[15M) Kf[23M) Vt[31M)

#define EPSV 1e-8f

typedef short bfrag __attribute__((ext_vector_type(8)));   // 8 bf16
typedef float cfrag __attribute__((ext_vector_type(16)));  // C/D 32x32
typedef int v2i __attribute__((ext_vector_type(2)));
typedef float v2f __attribute__((ext_vector_type(2)));

__device__ __forceinline__ short f2bf(float f) {
    __hip_bfloat16 h = __float2bfloat16(f);
    return *reinterpret_cast<short*>(&h);
}
__device__ __forceinline__ unsigned int pk2(short a, short b) {
    return (unsigned int)(unsigned short)a | ((unsigned int)(unsigned short)b << 16);
}
// async global->LDS DMA, 16B/lane: LDS dst = wave-uniform base + lane*16,
// global src = per-lane address (must include lane*16).
__device__ __forceinline__ void g2lds(const short* g, short* l) {
    __builtin_amdgcn_global_load_lds(
        (const __attribute__((address_space(1))) void*)g,
        (__attribute__((address_space(3))) void*)l, 16, 0, 0);
}

// ---------------------------------------------------------------------------
// prep: fused cvt/swizzle. grid.x = 3648, 256 thr.  (R16 verbatim)
__global__ __launch_bounds__(256) void prep(
    const float* __restrict__ hidden, const float* __restrict__ Wq,
    const float* __restrict__ Wk, const float* __restrict__ Wv,
    const float* __restrict__ dist,
    short* __restrict__ Xs, short* __restrict__ Wt, short* __restrict__ Db)
{
    __shared__ short Tl[32 * 72];
    const int bid = blockIdx.x, tid = threadIdx.x;

    if (bid < 2048) {                      // X: 128 m-tiles x 16 k-groups
        const int mt = bid >> 4, kg = bid & 15;
        const int m_l = tid >> 3, k8 = (tid & 7) * 8;
        const float* src = hidden + (size_t)(mt * 32 + m_l) * 1024 + kg * 64 + k8;
        float4 v0 = *(const float4*)src, v1 = *(const float4*)(src + 4);
        short o[8];
        o[0] = f2bf(v0.x); o[1] = f2bf(v0.y); o[2] = f2bf(v0.z); o[3] = f2bf(v0.w);
        o[4] = f2bf(v1.x); o[5] = f2bf(v1.y); o[6] = f2bf(v1.z); o[7] = f2bf(v1.w);
        *(bfrag*)&Tl[m_l * 72 + k8] = *(bfrag*)o;
        __syncthreads();
        const int l31 = tid & 31, q2 = (tid >> 5) & 1, kc = tid >> 6;
        bfrag r = *(const bfrag*)&Tl[l31 * 72 + kc * 16 + q2 * 8];
        *(bfrag*)(Xs + ((size_t)(mt * 64 + kg * 4 + kc) * 64 + q2 * 32 + l31) * 8) = r;
    } else if (bid < 3584) {               // W: 3 z x 32 n-tiles x 16 k-groups
        const int t = bid - 2048, z = t >> 9, nt = (t >> 4) & 31, kg = t & 15;
        const float* W = (z == 0) ? Wq : ((z == 1) ? Wk : Wv);
        const int k_l = tid >> 2, n8 = (tid & 3) * 8;
        const float* src = W + (size_t)(kg * 64 + k_l) * 1024 + nt * 32 + n8;
        float4 v0 = *(const float4*)src, v1 = *(const float4*)(src + 4);
        float vv[8] = {v0.x, v0.y, v0.z, v0.w, v1.x, v1.y, v1.z, v1.w};
#pragma unroll
        for (int i = 0; i < 8; i++)
            Tl[(n8 + i) * 72 + k_l] = f2bf(vv[i]);   // transpose into LDS
        __syncthreads();
        const int l31 = tid & 31, q2 = (tid >> 5) & 1, kc = tid >> 6;
        bfrag r = *(const bfrag*)&Tl[l31 * 72 + kc * 16 + q2 * 8];
        *(bfrag*)(Wt + (size_t)z * 1048576
                  + ((size_t)(nt * 64 + kg * 4 + kc) * 64 + q2 * 32 + l31) * 8) = r;
    } else {                               // dist: 2047*64 = 131008 elems
        const int idx = (bid - 3584) * 256 + tid;
        if (idx < 16376) {
            const float* src = dist + (size_t)idx * 8;
            float4 v0 = *(const float4*)src, v1 = *(const float4*)(src + 4);
            short o[8];
            o[0] = f2bf(v0.x); o[1] = f2bf(v0.y); o[2] = f2bf(v0.z); o[3] = f2bf(v0.w);
            o[4] = f2bf(v1.x); o[5] = f2bf(v1.y); o[6] = f2bf(v1.z); o[7] = f2bf(v1.w);
            *(bfrag*)(Db + (size_t)idx * 8) = *(bfrag*)o;
        }
    }
}

// ---------------------------------------------------------------------------
// QKV GEMM — R20: 3-buffer counted-vmcnt pipeline. 128x128 block, 4 waves.
// Phase p: vmcnt(4) (stage p retired; stage p+1 in flight) -> s_barrier ->
// issue STAGE(p+2) -> ds_read_b128 frags -> 8 MFMA. Never vmcnt(0) in loop.
// Layout: chunk (tile, kc) at tile*32768 + kc*512 shorts.
__global__ __launch_bounds__(256) void qkv_mfma(
    const short* __restrict__ Xs, const short* __restrict__ Wt,
    const float* __restrict__ bq, const float* __restrict__ bk,
    const float* __restrict__ bv,
    short* __restrict__ Qf, short* __restrict__ Kf, short* __restrict__ Vt)
{
    __shared__ alignas(16) short Ab[3][2][4][512];  // [buf][ksub][chunk][1KB]
    __shared__ alignas(16) short Bb[3][2][4][512];

    const int z = blockIdx.z;
    const short* W = Wt + (size_t)z * 1048576;
    const float* bias = (z == 0) ? bq : ((z == 1) ? bk : bv);
    // fold 1/sqrt(D) AND log2(e) into Q: 0.125 * 1.4426950408889634
    const float scale = (z == 0) ? 0.18033688011112042f : 1.0f;

    const int tid = threadIdx.x, lane = tid & 63, wid = tid >> 6;
    const int q2 = lane >> 5, l31 = lane & 31;
    const int wr = wid >> 1, wc = wid & 1;
    const int m0 = blockIdx.x * 128, n0 = blockIdx.y * 128;

    // tile-0 global bases (shorts); tile t at +t*32768, chunk kc at +kc*512
    const short* Ag = Xs + (size_t)(m0 >> 5) * 32768;
    const short* Bg = W  + (size_t)(n0 >> 5) * 32768;

    // stage phase p (k-subs 2p, 2p+1) into buf bi; wave w stages chunk w of
    // A and B for both k-subs (4 g2lds per wave, 16 chunks per block).
    auto STAGE = [&](int p, int bi) {
        const int k0 = p * 2;
#pragma unroll
        for (int j = 0; j < 2; j++) {
            g2lds(Ag + (size_t)wid * 32768 + (k0 + j) * 512 + lane * 8,
                  &Ab[bi][j][wid][0]);
            g2lds(Bg + (size_t)wid * 32768 + (k0 + j) * 512 + lane * 8,
                  &Bb[bi][j][wid][0]);
        }
    };

    cfrag acc[2][2];
#pragma unroll
    for (int i = 0; i < 2; i++)
#pragma unroll
        for (int j = 0; j < 2; j++)
#pragma unroll
            for (int e = 0; e < 16; e++) acc[i][j][e] = 0.f;

    STAGE(0, 0);
    STAGE(1, 1);

    for (int p = 0; p < 32; p++) {
        // own stage(p) writes retired (stage(p+1)'s 4 ops may remain);
        // barrier makes all waves' stage(p) chunks visible.
        if (p < 31) asm volatile("s_waitcnt vmcnt(4)" ::: "memory");
        else        asm volatile("s_waitcnt vmcnt(0)" ::: "memory");
        __builtin_amdgcn_s_barrier();
        // safe to overwrite buf (p-1)%3: all waves completed phase p-1
        // (its reads+MFMA precede barrier p in program order).
        if (p + 2 < 32) STAGE(p + 2, (p + 2) % 3);

        const int bi = p % 3;
#pragma unroll
        for (int j = 0; j < 2; j++) {
            bfrag a0 = *(const bfrag*)&Ab[bi][j][2 * wr + 0][lane * 8];
            bfrag a1 = *(const bfrag*)&Ab[bi][j][2 * wr + 1][lane * 8];
            bfrag b0 = *(const bfrag*)&Bb[bi][j][2 * wc + 0][lane * 8];
            bfrag b1 = *(const bfrag*)&Bb[bi][j][2 * wc + 1][lane * 8];
            acc[0][0] = __builtin_amdgcn_mfma_f32_32x32x16_bf16(a0, b0, acc[0][0], 0, 0, 0);
            acc[0][1] = __builtin_amdgcn_mfma_f32_32x32x16_bf16(a0, b1, acc[0][1], 0, 0, 0);
            acc[1][0] = __builtin_amdgcn_mfma_f32_32x32x16_bf16(a1, b0, acc[1][0], 0, 0, 0);
            acc[1][1] = __builtin_amdgcn_mfma_f32_32x32x16_bf16(a1, b1, acc[1][1], 0, 0, 0);
        }
    }

    // epilogue: +bias, (Q: x scale), cvt bf16, scatter frag-major per bh
#pragma unroll
    for (int nt = 0; nt < 2; nt++) {
        const int c = n0 + wc * 64 + nt * 32 + l31;    // channel
        const float bval = bias[c];
        const int h = c >> 6;
        const int d = nt * 32 + l31;                   // c & 63
#pragma unroll
        for (int mt = 0; mt < 2; mt++) {
            const int tok0 = m0 + wr * 64 + mt * 32;
            const int bb = tok0 >> 10, s_base = tok0 & 1023;
            const size_t bhbase = (size_t)(bb * 16 + h) * 65536;
            if (z < 2) {
                short* outp = (z == 0) ? Qf : Kf;
                const size_t fbase = bhbase
                    + ((size_t)((s_base >> 5) * 4 + (d >> 4)) * 64
                       + ((d >> 3) & 1) * 32) * 8 + (d & 7);
#pragma unroll
                for (int reg = 0; reg < 16; reg++) {
                    const int row = (reg & 3) + 8 * (reg >> 2) + 4 * q2;
                    outp[fbase + (size_t)row * 8] = f2bf((acc[mt][nt][reg] + bval) * scale);
                }
            } else {
                // V^T frag-major: elem (d, s): ((d>>5)*64 + (s>>4))*64*8 ...
#pragma unroll
                for (int g = 0; g < 4; g++) {
                    const float e0 = acc[mt][nt][4 * g + 0] + bval;
                    const float e1 = acc[mt][nt][4 * g + 1] + bval;
                    const float e2 = acc[mt][nt][4 * g + 2] + bval;
                    const float e3 = acc[mt][nt][4 * g + 3] + bval;
                    uint2 w2;
                    w2.x = pk2(f2bf(e0), f2bf(e1));
                    w2.y = pk2(f2bf(e2), f2bf(e3));
                    const size_t flat = bhbase
                        + ((size_t)(nt * 64 + (s_base >> 4) + (g >> 1)) * 64
                           + (g & 1) * 32 + l31) * 8 + 4 * q2;
                    *(uint2*)(Vt + flat) = w2;
                }
            }
        }
    }
}

// ---------------------------------------------------------------------------
// Fused attention — R17 verbatim (59.3us verified). grid (64 bh, 8 l-tiles),
// 256 thr (4 waves). Toeplitz ring by r, production one iter ahead, T as
// MFMA C-operand, K/V staged via global_load_lds double-buffer.
__global__ __launch_bounds__(256, 2) void attn_mfma(
    const short* __restrict__ Qf, const short* __restrict__ Kf,
    const short* __restrict__ Vt, const short* __restrict__ Db,
    const float* __restrict__ amask, const int* __restrict__ skim,
    float* __restrict__ out)
{
    __shared__ alignas(16) short Tb[128 * 132];   // per-(wave,lane) r-ring
    __shared__ alignas(16) short Kbuf[2][4096];   // 8KB per buf: K chunks
    __shared__ alignas(16) short Vbuf[2][4096];   // 8KB per buf: V chunks
    __shared__ float Lg[1024];                    // g[r] = exp(amask)*skim

    const int tid = threadIdx.x, lane = tid & 63, w = tid >> 6;
    const int q2 = lane >> 5, l31 = lane & 31;
    const int bh = blockIdx.x, b = bh >> 4, hh = bh & 15;
    const int l0 = blockIdx.y * 128;

    const short* Qg = Qf + (size_t)bh * 65536;
    const short* Kg = Kf + (size_t)bh * 65536;
    const short* Vg = Vt + (size_t)bh * 65536;

    // stage K/V for r-block rk into buf bi. 16 chunks of 1KB; wave w takes
    // chunks 4w..4w+3. c<8: K chunk (rk>>5)*4+c; c in [8,12): V mtd0 chunk
    // (rk>>4)+(c-8); c in [12,16): V mtd1 chunk 64+(rk>>4)+(c-12).
    auto STAGE = [&](int rk, int bi) {
        const int kbase = (rk >> 5) * 4, vbase = rk >> 4;
#pragma unroll
        for (int j = 0; j < 4; j++) {
            const int c = 4 * w + j;
            if (c < 8) {
                g2lds(Kg + (size_t)(kbase + c) * 512 + lane * 8,
                      &Kbuf[bi][c * 512]);
            } else if (c < 12) {
                g2lds(Vg + (size_t)(vbase + (c - 8)) * 512 + lane * 8,
                      &Vbuf[bi][(c - 8) * 512]);
            } else {
                g2lds(Vg + (size_t)(64 + vbase + (c - 12)) * 512 + lane * 8,
                      &Vbuf[bi][(c - 12 + 4) * 512]);
            }
        }
    };

    {
        const int r4 = tid * 4;
        float4 am = *(const float4*)(amask + b * 1024 + r4);
        int4 sk = *(const int4*)(skim + b * 1024 + r4);
        Lg[r4 + 0] = __expf(am.x) * (float)sk.x;
        Lg[r4 + 1] = __expf(am.y) * (float)sk.y;
        Lg[r4 + 2] = __expf(am.z) * (float)sk.z;
        Lg[r4 + 3] = __expf(am.w) * (float)sk.w;
    }
    __syncthreads();

    // Q B-frags (pre-scaled by log2e/8)
    bfrag qa[4];
#pragma unroll
    for (int c = 0; c < 4; c++)
        qa[c] = *(const bfrag*)(Qg + ((size_t)(((l0 >> 5) + w) * 4 + c) * 64 + lane) * 8);

    cfrag oacc[2];
#pragma unroll
    for (int mt = 0; mt < 2; mt++)
#pragma unroll
        for (int e = 0; e < 16; e++) oacc[mt][e] = 0.f;
    v2f es01 = {0.f, 0.f}, es23 = {0.f, 0.f};

    const int Lband = l0 + 32 * w;          // wave's first l-column
    const int lg = Lband + l31;             // this lane's l-column
    const int rowb = (32 * w + l31) * 132;  // private ring row (shorts)

    for (int r0 = -128; r0 < 1024; r0 += 64) {
        const bool produce = r0 < 960;
        const int cur = (r0 >> 6) & 1;      // consume buffer (valid r0>=0)

        // ---- stage next iteration's K/V (async DMA, full-iter cover) ----
        if (r0 + 64 >= 0 && r0 + 64 < 1024)
            STAGE(r0 + 64, ((r0 + 64) >> 6) & 1);

        // ---- issue production's Db loads early (independent) ----
        bfrag pb[2][4];
        if (produce) {
#pragma unroll
            for (int mt = 0; mt < 2; mt++) {
                const int D0 = Lband - r0 - 128 + 32 * mt;   // dist block base
                const int er = min(max(D0 + l31 + 1023, 0), 2046);
#pragma unroll
                for (int kc = 0; kc < 4; kc++)
                    pb[mt][kc] = *(const bfrag*)(Db + (size_t)er * 64 + kc * 16 + q2 * 8);
            }
        }

        if (r0 >= 0) {
            // ---- K, V frags from staged LDS; ring reads; all hoisted ----
            bfrag kb[2][4], vbl[4][2];
            v2i trr[2][4];
#pragma unroll
            for (int mt = 0; mt < 2; mt++)
#pragma unroll
                for (int kc = 0; kc < 4; kc++)
                    kb[mt][kc] = *(const bfrag*)&Kbuf[cur][(mt * 4 + kc) * 512 + lane * 8];
#pragma unroll
            for (int kc = 0; kc < 4; kc++)
#pragma unroll
                for (int mtd = 0; mtd < 2; mtd++)
                    vbl[kc][mtd] = *(const bfrag*)&Vbuf[cur][(mtd * 4 + kc) * 512 + lane * 8];
#pragma unroll
            for (int mt = 0; mt < 2; mt++)
#pragma unroll
                for (int g = 0; g < 4; g++)
                    trr[mt][g] = *(const v2i*)&Tb[rowb
                        + ((r0 + 32 * mt + 8 * g + 4 * q2) & 127)];

            // ---- per 32-r block: scores (C=T), softmax, relayout, PV ----
#pragma unroll
            for (int mt = 0; mt < 2; mt++) {
                cfrag sfr;
#pragma unroll
                for (int g = 0; g < 4; g++) {
                    const v2i t2 = trr[mt][g];
                    sfr[4 * g + 0] = __builtin_bit_cast(float, (unsigned)t2[0] << 16);
                    sfr[4 * g + 1] = __builtin_bit_cast(float, (unsigned)t2[0] & 0xffff0000u);
                    sfr[4 * g + 2] = __builtin_bit_cast(float, (unsigned)t2[1] << 16);
                    sfr[4 * g + 3] = __builtin_bit_cast(float, (unsigned)t2[1] & 0xffff0000u);
                }
                __builtin_amdgcn_s_setprio(1);
#pragma unroll
                for (int kc = 0; kc < 4; kc++)
                    sfr = __builtin_amdgcn_mfma_f32_32x32x16_bf16(
                        kb[mt][kc], qa[kc], sfr, 0, 0, 0);
                __builtin_amdgcn_s_setprio(0);

                unsigned int P[4][2];
#pragma unroll
                for (int g = 0; g < 4; g++) {
                    const int rb = r0 + 32 * mt + 8 * g + 4 * q2;
                    float4 g4 = *(const float4*)&Lg[rb];
                    float ev0 = __builtin_amdgcn_exp2f(sfr[4 * g + 0]) * g4.x;
                    float ev1 = __builtin_amdgcn_exp2f(sfr[4 * g + 1]) * g4.y;
                    float ev2 = __builtin_amdgcn_exp2f(sfr[4 * g + 2]) * g4.z;
                    float ev3 = __builtin_amdgcn_exp2f(sfr[4 * g + 3]) * g4.w;
                    es01 += (v2f){ev0, ev1};
                    es23 += (v2f){ev2, ev3};
                    P[g][0] = pk2(f2bf(ev0), f2bf(ev1));
                    P[g][1] = pk2(f2bf(ev2), f2bf(ev3));
                }
                // in-register relayout: score C-frag -> PV B-frag
#pragma unroll
                for (int c = 0; c < 2; c++) {
                    v2i s0 = __builtin_amdgcn_permlane32_swap(
                        (int)P[2 * c][0], (int)P[2 * c + 1][0], false, false);
                    v2i s1 = __builtin_amdgcn_permlane32_swap(
                        (int)P[2 * c][1], (int)P[2 * c + 1][1], false, false);
                    union { bfrag f; int d[4]; } u;
                    u.d[0] = s0[0]; u.d[1] = s1[0]; u.d[2] = s0[1]; u.d[3] = s1[1];
                    const int kc = 2 * mt + c;
                    __builtin_amdgcn_s_setprio(1);
#pragma unroll
                    for (int mtd = 0; mtd < 2; mtd++)
                        oacc[mtd] = __builtin_amdgcn_mfma_f32_32x32x16_bf16(
                            vbl[kc][mtd], u.f, oacc[mtd], 0, 0, 0);
                    __builtin_amdgcn_s_setprio(0);
                }
            }
        }

        // ---- production: T window for [r0+64, r0+127] (after gathers) ----
        if (produce) {
#pragma unroll
            for (int mt = 0; mt < 2; mt++) {
                cfrag t;
#pragma unroll
                for (int e = 0; e < 16; e++) t[e] = 0.f;
                __builtin_amdgcn_s_setprio(1);
#pragma unroll
                for (int kc = 0; kc < 4; kc++)
                    t = __builtin_amdgcn_mfma_f32_32x32x16_bf16(
                        pb[mt][kc], qa[kc], t, 0, 0, 0);
                __builtin_amdgcn_s_setprio(0);
#pragma unroll
                for (int e = 0; e < 16; e++) {
                    const int rr = (e & 3) + 8 * (e >> 2) + 4 * q2;
                    Tb[rowb + ((l31 + r0 - 32 * mt - rr) & 127)] = f2bf(t[e]);
                }
            }
        }

        // barrier: (a) completes next iter's staged DMA (implicit vmcnt
        // drain), (b) orders buf reuse across waves. Tb is wave-private.
        __syncthreads();
    }

    // ---- finalize ----
    float esum = (es01[0] + es01[1]) + (es23[0] + es23[1]);
    const float den = EPSV + esum + __shfl_xor(esum, 32);
    const float inv = 1.0f / den;
    float* ob = out + ((size_t)(b * 1024 + lg) * 1024) + hh * 64;
#pragma unroll
    for (int mtd = 0; mtd < 2; mtd++) {
#pragma unroll
        for (int g = 0; g < 4; g++) {
            float4 o;
            o.x = oacc[mtd][4 * g + 0] * inv;
            o.y = oacc[mtd][4 * g + 1] * inv;
            o.z = oacc[mtd][4 * g + 2] * inv;
            o.w = oacc[mtd][4 * g + 3] * inv;
            *(float4*)(ob + 32 * mtd + 8 * g + 4 * q2) = o;
        }
    }
}

// ---------------------------------------------------------------------------
extern "C" void kernel_launch(void* const* d_in, const int* in_sizes, int n_in,
                              void* d_out, int out_size, void* d_ws, size_t ws_size,
                              hipStream_t stream) {
    const float* hidden = (const float*)d_in[0];
    const float* amask  = (const float*)d_in[1];
    const int*   skim   = (const int*)d_in[2];
    const float* Wq     = (const float*)d_in[3];
    const float* bq     = (const float*)d_in[4];
    const float* Wk     = (const float*)d_in[5];
    const float* bk     = (const float*)d_in[6];
    const float* Wv     = (const float*)d_in[7];
    const float* bv     = (const float*)d_in[8];
    const float* dist   = (const float*)d_in[9];
    float* out = (float*)d_out;

    char* w = (char*)d_ws;
    short* Xs  = (short*)(w);                        // 8 MB frag-major X
    short* Wt  = (short*)(w + ((size_t)8 << 20));    // 6 MB frag-major W^T
    short* Db  = (short*)(w + ((size_t)14 << 20));   // 0.25 MB dist bf16
    short* Qf  = (short*)(w + ((size_t)15 << 20));   // 8 MB frag-major Q
    short* Kf  = (short*)(w + ((size_t)23 << 20));   // 8 MB frag-major K
    short* Vt  = (short*)(w + ((size_t)31 << 20));   // 8 MB frag-major V^T

    prep<<<3648, 256, 0, stream>>>(hidden, Wq, Wk, Wv, dist, Xs, Wt, Db);
    qkv_mfma<<<dim3(32, 8, 3), 256, 0, stream>>>(Xs, Wt, bq, bk, bv, Qf, Kf, Vt);
    attn_mfma<<<dim3(64, 8), 256, 0, stream>>>(Qf, Kf, Vt, Db, amask, skim, out);
}